// Round 10
// baseline (901.801 us; speedup 1.0000x reference)
//
#include <hip/hip_runtime.h>

#define B_    2
#define C0_   64
#define C4_   256
#define H_    160
#define W_    320
#define G_    4
#define HW_   (H_*W_)
#define NROWS_ (B_*H_)      // 320
#define EPS_  1e-5f

typedef float f32x4 __attribute__((ext_vector_type(4)));
typedef short s16x8 __attribute__((ext_vector_type(8)));
typedef _Float16 h16x8 __attribute__((ext_vector_type(8)));
typedef _Float16 h16x4 __attribute__((ext_vector_type(4)));

// workspace sizes (in floats)
#define WFQ_SZ  36864       // f32 [g][tap9][o16][ic64]
#define WB_SZ   73728       // bf16 conv1 weights (147456 shorts)
#define W2B_SZ  20480       // bf16 fused conv2 weights (40960 shorts)
#define AB_SZ   1024
#define BF_SZ   64
#define PB_SZ   8192        // bnstats partials: 4096 float2
#define T1_SZ   13107200    // bf16 t1 [b][g][h][w][ic64]; later: xh fp16 planes
#define CATB_SZ 13107200    // bf16 catb; later: Q/K split planes
#define QK_SZ   ((size_t)B_*C0_*HW_)   // 6553600
#define RS_SZ   ((size_t)NROWS_*W_)    // 102400
#define CSP_SZ  ((size_t)NROWS_*5*W_)  // 512000

__device__ __forceinline__ unsigned f2bf1(float x) {
  unsigned u = __float_as_uint(x);
  return (u + 0x7FFFu + ((u >> 16) & 1u)) >> 16;
}
__device__ __forceinline__ unsigned packbf(float lo, float hi) {
  return f2bf1(lo) | (f2bf1(hi) << 16);
}
// swizzled short-index into a [row][64] 2B plane: XOR 16B-chunk by (row&7)
__device__ __forceinline__ int psw(int r, int c) {
  return (r << 6) + (((c >> 3) ^ (r & 7)) << 3) + (c & 7);
}

// ---------------------------------------------------------------------------
// wtrans: Wb bf16 [g][tap][oc][ic]; WfQ/WfK f32 [g][tap][o16][ic] (proj-folded)
__global__ __launch_bounds__(256) void wtrans_kernel(
    const float* __restrict__ w1, const float* __restrict__ w2,
    const float* __restrict__ bq, const float* __restrict__ bs,
    unsigned short* __restrict__ Wb, float* __restrict__ WfQ, float* __restrict__ WfK) {
  int idx = blockIdx.x * 256 + threadIdx.x;
  if (idx < 147456) {
    int ic = idx & 63, oc = (idx >> 6) & 63, tap = (idx >> 12) % 9, g = idx / 36864;
    float v = w1[((size_t)(g*64 + oc) * 64 + ic) * 9 + tap];
    Wb[idx] = (unsigned short)f2bf1(v);
  }
  if (idx < 36864) {
    int ic = idx & 63, o = (idx >> 6) & 15, tap = (idx >> 10) % 9, g = idx / 9216;
    const float* w2p = w2 + ((size_t)(g*64) * 64 + ic) * 9 + tap;   // + oc*576
    const float* bqp = bq + (size_t)(g*16 + o) * 64;
    const float* bsp = bs + (size_t)(g*16 + o) * 64;
    float sq = 0.f, sk = 0.f;
    for (int oc = 0; oc < 64; ++oc) {
      float wv = w2p[(size_t)oc * 576];
      sq = fmaf(bqp[oc], wv, sq);
      sk = fmaf(bsp[oc], wv, sk);
    }
    WfQ[idx] = sq;
    WfK[idx] = sk;
  }
}

// ---------------------------------------------------------------------------
// bnstats stage 1: per (side, channel, hw-chunk) partial sum/sumsq, float4 loads.
__global__ __launch_bounds__(256) void bnstats1_kernel(
    const float* __restrict__ catL, const float* __restrict__ catR,
    float2* __restrict__ pb) {
  const int bid = blockIdx.x;
  const int sc = bid >> 3, ck = bid & 7;
  const int side = sc >> 8, c = sc & 255;
  const float* base = (side ? catR : catL) + (size_t)c * HW_ + ck * (HW_/8);
  float s = 0.f, s2 = 0.f;
  for (int i = threadIdx.x; i < 1600; i += 256) {
    const float4 v0 = *(const float4*)&base[4*i];
    const float4 v1 = *(const float4*)&base[(size_t)C4_*HW_ + 4*i];
    s  += (v0.x + v0.y) + (v0.z + v0.w) + (v1.x + v1.y) + (v1.z + v1.w);
    float t0 = fmaf(v0.x, v0.x, v0.y*v0.y) + fmaf(v0.z, v0.z, v0.w*v0.w);
    float t1 = fmaf(v1.x, v1.x, v1.y*v1.y) + fmaf(v1.z, v1.z, v1.w*v1.w);
    s2 += t0 + t1;
  }
  #pragma unroll
  for (int o = 32; o; o >>= 1) { s += __shfl_down(s, o); s2 += __shfl_down(s2, o); }
  __shared__ float rs[4], rs2[4];
  const int wid = threadIdx.x >> 6;
  if ((threadIdx.x & 63) == 0) { rs[wid] = s; rs2[wid] = s2; }
  __syncthreads();
  if (threadIdx.x == 0)
    pb[bid] = make_float2(rs[0]+rs[1]+rs[2]+rs[3], rs2[0]+rs2[1]+rs2[2]+rs2[3]);
}

__global__ __launch_bounds__(256) void bnstats2_kernel(
    const float2* __restrict__ pb, const float* __restrict__ gamma,
    const float* __restrict__ beta, float* __restrict__ ab) {
  const int sc = blockIdx.x * 256 + threadIdx.x;
  if (sc >= 512) return;
  const int side = sc >> 8, c = sc & 255;
  float s = 0.f, s2 = 0.f;
  #pragma unroll
  for (int k = 0; k < 8; ++k) {
    const float2 p = pb[sc*8 + k];
    s += p.x; s2 += p.y;
  }
  const float inv_n = 1.f / (float)(2*HW_);
  const float mu  = s * inv_n;
  const float var = s2 * inv_n - mu*mu;
  const float a = gamma[c] * rsqrtf(var + EPS_);
  ab[side*512 + c]       = a;
  ab[side*512 + 256 + c] = beta[c] - mu*a;
}

// ---------------------------------------------------------------------------
// bnapply: catb[b][g][px][ic64] = bf16( a*cat + shift ). One side per launch.
__global__ __launch_bounds__(256) void bnapply_kernel(
    const float* __restrict__ cat, const float* __restrict__ abs_,
    unsigned short* __restrict__ catb) {
  const int z = blockIdx.z;
  const int b = z >> 2, g = z & 3;
  const int tid = threadIdx.x;
  const int px = blockIdx.x * 64 + (tid & 63);
  const int ic0 = (tid >> 6) * 16;
  const float* src = cat + ((size_t)b*C4_ + g*64 + ic0) * HW_ + px;
  const float* abp = abs_ + g*64 + ic0;
  unsigned short* dst = catb + (((size_t)(b*4 + g)*HW_ + px) << 6) + ic0;
  unsigned pk[8];
  #pragma unroll
  for (int j = 0; j < 8; ++j) {
    const float2 a2 = *(const float2*)&abp[2*j];
    const float2 s2 = *(const float2*)&abp[256 + 2*j];
    float v0 = fmaf(a2.x, src[(size_t)(2*j)*HW_],   s2.x);
    float v1 = fmaf(a2.y, src[(size_t)(2*j+1)*HW_], s2.y);
    pk[j] = packbf(v0, v1);
  }
  *(uint4*)&dst[0] = *(uint4*)&pk[0];
  *(uint4*)&dst[8] = *(uint4*)&pk[4];
}

// ---------------------------------------------------------------------------
// prep2: W2bQ/K bf16 [g][tap10][o][ic]; bf[o] = proj_bias + sum_c w*b2_c
__global__ __launch_bounds__(256) void prep2_kernel(
    const float* __restrict__ bq, const float* __restrict__ bs,
    const float* __restrict__ bqb, const float* __restrict__ bsb,
    const float* __restrict__ b2,
    const float* __restrict__ WfQ, const float* __restrict__ WfK,
    unsigned short* __restrict__ W2bQ, unsigned short* __restrict__ W2bK,
    float* __restrict__ bfQ, float* __restrict__ bfK) {
  int idx = blockIdx.x*256 + threadIdx.x;
  if (idx < 40960) {
    int ic = idx & 63, o = (idx >> 6) & 15, tap = (idx >> 10) % 10, g = idx / 10240;
    float vq, vk;
    if (tap < 9) {
      int src = ((g*9 + tap)*16 + o)*64 + ic;
      vq = WfQ[src]; vk = WfK[src];
    } else {
      vq = bq[(size_t)(g*16 + o)*64 + ic];
      vk = bs[(size_t)(g*16 + o)*64 + ic];
    }
    W2bQ[idx] = (unsigned short)f2bf1(vq);
    W2bK[idx] = (unsigned short)f2bf1(vk);
  }
  if (idx < 128) {
    int side = idx >> 6, co = idx & 63, g = co >> 4, o = co & 15;
    const float* w = side ? bs : bq;
    float s = (side ? bsb : bqb)[co];
    for (int c2 = 0; c2 < 64; ++c2) {
      int ch = g*64 + c2;
      s = fmaf(w[(size_t)(g*16 + o)*64 + c2], b2[ch], s);
    }
    (side ? bfK : bfQ)[co] = s;
  }
}

// ---------------------------------------------------------------------------
// conv1 MFMA: t1[b][g][h][w][oc64](bf16) = leaky(gconv3x3(catb) + b1)
__global__ __launch_bounds__(256) void conv1_mfma(
    const unsigned short* __restrict__ catb,
    const unsigned short* __restrict__ Wb, const float* __restrict__ bias,
    unsigned short* __restrict__ t1) {
  const int b = blockIdx.z >> 2, g = blockIdx.z & 3;
  const int h0 = blockIdx.y * 2, w0 = blockIdx.x * 64;
  const int tid = threadIdx.x;
  const int lane = tid & 63, wv = tid >> 6;
  const int m0 = wv * 16;
  const int m = lane & 15, kg = lane >> 4;
  __shared__ short Xs[4*66*72];   // [r4][c66][icpad72]

  const unsigned short* catbg = catb + (((size_t)(b*4 + g)*H_) << 6) * W_;
  for (int u = tid; u < 264*8; u += 256) {
    int rc = u >> 3, j = u & 7;
    int r = rc / 66, c = rc - r*66;
    int gh = h0 - 1 + r, gw = w0 - 1 + c;
    s16x8 v = {};
    if (gh >= 0 && gh < H_ && gw >= 0 && gw < W_)
      v = *(const s16x8*)&catbg[(((size_t)gh*W_ + gw) << 6) + j*8];
    *(s16x8*)&Xs[rc*72 + j*8] = v;
  }

  s16x8 afrag[18];
  #pragma unroll
  for (int s = 0; s < 18; ++s) {
    const int tap = s >> 1, ic0 = (s & 1)*32 + kg*8;
    afrag[s] = *(const s16x8*)&Wb[(((size_t)g*9 + tap)*64 + m0 + m)*64 + ic0];
  }
  __syncthreads();

  f32x4 acc[8] = {};
  #pragma unroll
  for (int s = 0; s < 18; ++s) {
    const int tap = s >> 1, dh = tap / 3, dw = tap - dh*3;
    const int ic0 = (s & 1)*32 + kg*8;
    #pragma unroll
    for (int t = 0; t < 8; ++t) {
      const int px = t*16 + m;
      const int r = px >> 6, wl = px & 63;
      const s16x8 bfrag = *(const s16x8*)&Xs[((r + dh)*66 + wl + dw)*72 + ic0];
      acc[t] = __builtin_amdgcn_mfma_f32_16x16x32_bf16(afrag[s], bfrag, acc[t], 0, 0, 0);
    }
  }

  const int ocq = m0 + kg*4;
  const float4 b4 = *(const float4*)&bias[g*64 + ocq];
  const float bb[4] = {b4.x, b4.y, b4.z, b4.w};
  #pragma unroll
  for (int t = 0; t < 8; ++t) {
    const int px = t*16 + m;
    const int h = h0 + (px >> 6), w = w0 + (px & 63);
    float v[4];
    #pragma unroll
    for (int r = 0; r < 4; ++r) {
      float x = acc[t][r] + bb[r];
      v[r] = (x >= 0.f) ? x : 0.1f * x;
    }
    const size_t base = ((((size_t)(b*4 + g)*H_ + h)*W_ + w) << 6) + ocq;
    uint2 pk; pk.x = packbf(v[0], v[1]); pk.y = packbf(v[2], v[3]);
    *(uint2*)&t1[base] = pk;
  }
}

// ---------------------------------------------------------------------------
// conv2 MFMA + folded 1x1 proj + residual-as-K (residual data = catb)
__global__ __launch_bounds__(256) void conv2_mfma(
    const unsigned short* __restrict__ t1, const unsigned short* __restrict__ catb,
    const unsigned short* __restrict__ W2b,
    const float* __restrict__ bf, float* __restrict__ qout) {
  const int b = blockIdx.z >> 2, g = blockIdx.z & 3;
  const int h0 = blockIdx.y * 2, w0 = blockIdx.x * 64;
  const int tid = threadIdx.x;
  const int lane = tid & 63, wv = tid >> 6;
  const int m = lane & 15, kg = lane >> 4;
  __shared__ short Ys[4*66*72];
  __shared__ short Rs[128*72];

  const unsigned short* t1g = t1 + (((size_t)(b*4 + g)*H_) << 6) * W_;
  const unsigned short* catbg = catb + (((size_t)(b*4 + g)*H_) << 6) * W_;
  for (int u = tid; u < 264*8; u += 256) {
    int rc = u >> 3, j = u & 7;
    int r = rc / 66, c = rc - r*66;
    int gh = h0 - 1 + r, gw = w0 - 1 + c;
    s16x8 v = {};
    if (gh >= 0 && gh < H_ && gw >= 0 && gw < W_)
      v = *(const s16x8*)&t1g[(((size_t)gh*W_ + gw) << 6) + j*8];
    *(s16x8*)&Ys[(rc*72) + j*8] = v;
  }
  for (int u = tid; u < 128*8; u += 256) {
    int px = u >> 3, j = u & 7;
    int gh = h0 + (px >> 6), gw = w0 + (px & 63);
    *(s16x8*)&Rs[px*72 + j*8] =
        *(const s16x8*)&catbg[(((size_t)gh*W_ + gw) << 6) + j*8];
  }

  s16x8 afrag[20];
  #pragma unroll
  for (int s = 0; s < 20; ++s) {
    const int tap = (s < 18) ? (s >> 1) : 9;
    const int ic0 = (s < 18) ? ((s & 1)*32 + kg*8) : ((s - 18)*32 + kg*8);
    afrag[s] = *(const s16x8*)&W2b[(((size_t)g*10 + tap)*16 + m)*64 + ic0];
  }
  __syncthreads();

  f32x4 acc[2] = {};
  #pragma unroll
  for (int s = 0; s < 18; ++s) {
    const int tap = s >> 1, dh = tap / 3, dw = tap - dh*3;
    const int ic0 = (s & 1)*32 + kg*8;
    #pragma unroll
    for (int t = 0; t < 2; ++t) {
      const int px = (wv*2 + t)*16 + m;
      const int r = px >> 6, wl = px & 63;
      const s16x8 bfrag = *(const s16x8*)&Ys[((r + dh)*66 + wl + dw)*72 + ic0];
      acc[t] = __builtin_amdgcn_mfma_f32_16x16x32_bf16(afrag[s], bfrag, acc[t], 0, 0, 0);
    }
  }
  #pragma unroll
  for (int s = 18; s < 20; ++s) {
    const int ic0 = (s - 18)*32 + kg*8;
    #pragma unroll
    for (int t = 0; t < 2; ++t) {
      const int px = (wv*2 + t)*16 + m;
      const s16x8 bfrag = *(const s16x8*)&Rs[px*72 + ic0];
      acc[t] = __builtin_amdgcn_mfma_f32_16x16x32_bf16(afrag[s], bfrag, acc[t], 0, 0, 0);
    }
  }

  const int ocq = kg*4;
  const float4 q4 = *(const float4*)&bf[g*16 + ocq];
  const float qb[4] = {q4.x, q4.y, q4.z, q4.w};
  #pragma unroll
  for (int t = 0; t < 2; ++t) {
    const int px = (wv*2 + t)*16 + m;
    const int h = h0 + (px >> 6), w = w0 + (px & 63);
    #pragma unroll
    for (int r = 0; r < 4; ++r) {
      const int oc = g*16 + ocq + r;
      qout[((size_t)(b*64 + oc)*H_ + h)*W_ + w] = acc[t][r] + qb[r];
    }
  }
}

// ---------------------------------------------------------------------------
__global__ __launch_bounds__(64) void rowmean_kernel(float* __restrict__ q) {
  float* p = q + (size_t)blockIdx.x * W_;
  const int lane = threadIdx.x;
  float v[5]; float s = 0.f;
  #pragma unroll
  for (int k = 0; k < 5; ++k) { v[k] = p[lane + 64*k]; s += v[k]; }
  #pragma unroll
  for (int o = 32; o; o >>= 1) s += __shfl_xor(s, o);
  const float m = s * (1.f/320.f);
  #pragma unroll
  for (int k = 0; k < 5; ++k) p[lane + 64*k] = v[k] - m;
}

// ---------------------------------------------------------------------------
// qksplit: f32 [b][c][h][w] (row-mean'd) -> split bf16 planes [row][u][c]
__global__ __launch_bounds__(256) void qksplit_kernel(
    const float* __restrict__ src,
    unsigned short* __restrict__ dstH, unsigned short* __restrict__ dstL) {
  const int ut = blockIdx.x, row = blockIdx.y;
  const int u0 = ut * 64;
  const int b = row / H_, hh = row - b*H_;
  const int tid = threadIdx.x;
  __shared__ float Tf[64][65];   // [c][u]
  for (int i = tid; i < 1024; i += 256) {
    int c = i >> 4, q = i & 15;
    *(float4*)&Tf[c][4*q] =
        *(const float4*)&src[((size_t)(b*64 + c)*H_ + hh)*W_ + u0 + 4*q];
  }
  __syncthreads();
  for (int i = tid; i < 512; i += 256) {
    int u = i >> 3, j = i & 7;
    unsigned hi[8], lo[8];
    #pragma unroll
    for (int k = 0; k < 8; ++k) {
      float v = Tf[j*8 + k][u];
      unsigned hh32 = f2bf1(v);
      hi[k] = hh32;
      lo[k] = f2bf1(v - __uint_as_float(hh32 << 16));
    }
    unsigned ph[4], pl[4];
    #pragma unroll
    for (int k = 0; k < 4; ++k) {
      ph[k] = hi[2*k] | (hi[2*k+1] << 16);
      pl[k] = lo[2*k] | (lo[2*k+1] << 16);
    }
    const size_t dst = ((size_t)row*320 + u0 + u)*64 + j*8;
    *(uint4*)&dstH[dst] = *(uint4*)&ph[0];
    *(uint4*)&dstL[dst] = *(uint4*)&pl[0];
  }
}

// xcvt: x_left/x_right f32 -> fp16 planes (same [b][c][h][w] layout)
__global__ __launch_bounds__(256) void xcvt_kernel(
    const float* __restrict__ xl, const float* __restrict__ xr,
    _Float16* __restrict__ dl, _Float16* __restrict__ dr) {
  const size_t i8 = ((size_t)blockIdx.x*256 + threadIdx.x) * 8;
  if (i8 >= QK_SZ) return;
  float4 a = *(const float4*)&xl[i8], b4 = *(const float4*)&xl[i8+4];
  h16x8 o = {(_Float16)a.x,(_Float16)a.y,(_Float16)a.z,(_Float16)a.w,
             (_Float16)b4.x,(_Float16)b4.y,(_Float16)b4.z,(_Float16)b4.w};
  *(h16x8*)&dl[i8] = o;
  a = *(const float4*)&xr[i8]; b4 = *(const float4*)&xr[i8+4];
  h16x8 o2 = {(_Float16)a.x,(_Float16)a.y,(_Float16)a.z,(_Float16)a.w,
              (_Float16)b4.x,(_Float16)b4.y,(_Float16)b4.z,(_Float16)b4.w};
  *(h16x8*)&dr[i8] = o2;
}

// ---------------------------------------------------------------------------
// stats: register Q frags + global K frags. XCD-chunked swizzle: all 5 ub-blocks
// of a row land on the same XCD (1600 = 8 * 200, bijective).
__global__ __launch_bounds__(256, 4) void stats_kernel(
    const unsigned short* __restrict__ QHg, const unsigned short* __restrict__ QLg,
    const unsigned short* __restrict__ KHg, const unsigned short* __restrict__ KLg,
    float* __restrict__ rsum, float* __restrict__ cspart) {
  const int bid = blockIdx.x;
  const int swz = (bid & 7) * 200 + (bid >> 3);
  const int row = swz / 5, ub = swz - row*5;
  const int u0 = ub * 64;
  const int tid = threadIdx.x;
  const int lane = tid & 63, wv = tid >> 6;
  const int l15 = lane & 15, l4 = lane >> 4;
  __shared__ float rsw[256];
  const size_t pbase = (size_t)row * 320 * 64;

  s16x8 qh[4][2], ql[4][2];
  #pragma unroll
  for (int t = 0; t < 4; ++t) {
    const size_t a = pbase + (size_t)(u0 + t*16 + l15)*64 + l4*8;
    qh[t][0] = *(const s16x8*)&QHg[a];
    qh[t][1] = *(const s16x8*)&QHg[a + 32];
    ql[t][0] = *(const s16x8*)&QLg[a];
    ql[t][1] = *(const s16x8*)&QLg[a + 32];
  }
  float rp[4] = {};
  for (int vb = 0; vb < 5; ++vb) {
    const size_t ka = pbase + (size_t)(vb*64 + (wv << 4) + l15)*64 + l4*8;
    const s16x8 kh0 = *(const s16x8*)&KHg[ka];
    const s16x8 kh1 = *(const s16x8*)&KHg[ka + 32];
    const s16x8 kl0 = *(const s16x8*)&KLg[ka];
    const s16x8 kl1 = *(const s16x8*)&KLg[ka + 32];
    float cp[4] = {};
    #pragma unroll
    for (int t = 0; t < 4; ++t) {
      f32x4 s = {};
      s = __builtin_amdgcn_mfma_f32_16x16x32_bf16(kh0, qh[t][0], s, 0, 0, 0);
      s = __builtin_amdgcn_mfma_f32_16x16x32_bf16(kh1, qh[t][1], s, 0, 0, 0);
      s = __builtin_amdgcn_mfma_f32_16x16x32_bf16(kl0, qh[t][0], s, 0, 0, 0);
      s = __builtin_amdgcn_mfma_f32_16x16x32_bf16(kl1, qh[t][1], s, 0, 0, 0);
      s = __builtin_amdgcn_mfma_f32_16x16x32_bf16(kh0, ql[t][0], s, 0, 0, 0);
      s = __builtin_amdgcn_mfma_f32_16x16x32_bf16(kh1, ql[t][1], s, 0, 0, 0);
      float e0 = __expf(s[0]), e1 = __expf(s[1]), e2 = __expf(s[2]), e3 = __expf(s[3]);
      rp[t] += e0 + e1 + e2 + e3;
      cp[0] += e0; cp[1] += e1; cp[2] += e2; cp[3] += e3;
    }
    #pragma unroll
    for (int r = 0; r < 4; ++r) {
      float v = cp[r];
      v += __shfl_xor(v, 1); v += __shfl_xor(v, 2);
      v += __shfl_xor(v, 4); v += __shfl_xor(v, 8);
      cp[r] = v;
    }
    if (l15 == 0) {
      f32x4 cw = {cp[0], cp[1], cp[2], cp[3]};
      *(f32x4*)&cspart[((size_t)row*5 + ub)*W_ + vb*64 + (wv << 4) + (l4 << 2)] = cw;
    }
  }
  #pragma unroll
  for (int t = 0; t < 4; ++t) {
    float v = rp[t];
    v += __shfl_xor(v, 16); v += __shfl_xor(v, 32);
    rp[t] = v;
  }
  if (l4 == 0) {
    #pragma unroll
    for (int t = 0; t < 4; ++t) rsw[(wv << 6) + (t << 4) + l15] = rp[t];
  }
  __syncthreads();
  if (tid < 64)
    rsum[(size_t)row*W_ + u0 + tid] = rsw[tid] + rsw[64+tid] + rsw[128+tid] + rsw[192+tid];
}

__global__ __launch_bounds__(256) void csreduce_kernel(
    const float* __restrict__ csp, float* __restrict__ csum) {
  int idx = blockIdx.x*256 + threadIdx.x;
  if (idx >= (int)RS_SZ) return;
  int row = idx / W_, v = idx - row*W_;
  float s = 0.f;
  #pragma unroll
  for (int ub = 0; ub < 5; ++ub) s += csp[((size_t)row*5 + ub)*W_ + v];
  csum[idx] = s;
}

// ---------------------------------------------------------------------------
__device__ __forceinline__ int halo_u(int k, int u0) {
  if (k < 64) return u0 + k;
  return (k == 64) ? (u0-2) : (k == 65) ? (u0-1) : (k == 66) ? (u0+64) : (u0+65);
}

// attn: Q frags reloaded per (vb,t) from global planes (L1/L2-hit; NO persistent
// 80-VGPR array -> no spill). XCD-chunked swizzle for K/x-plane L2 locality.
__global__ __launch_bounds__(256, 4) void attn_kernel(
    const unsigned short* __restrict__ QHg, const unsigned short* __restrict__ QLg,
    const unsigned short* __restrict__ KHg, const unsigned short* __restrict__ KLg,
    const float* __restrict__ rsump, const float* __restrict__ csump,
    const _Float16* __restrict__ xh, const float* __restrict__ xblend,
    float* __restrict__ outp) {
  const int bid = blockIdx.x;
  const int swz = (bid & 7) * 200 + (bid >> 3);
  const int row = swz / 5, ub = swz - row*5;
  const int b = row / H_, h = row - b*H_;
  const int u0 = ub * 64;
  const int tid = threadIdx.x;
  const int lane = tid & 63, wv = tid >> 6;
  const int l15 = lane & 15, l4 = lane >> 4;

  __shared__ _Float16 Ph[68*64];    // P fp16 [u 0..67][v], psw-swizzled
  __shared__ float rinv[80];        // 68..79 = 0
  __shared__ float Vw[256], Vt[64];

  const size_t rowoff = (size_t)b*C0_*HW_ + (size_t)h*W_;
  const size_t pbase = (size_t)row * 320 * 64;
  const float* rsrow = rsump + (size_t)row*W_;
  const float* csrow = csump + (size_t)row*W_;

  if (tid < 80) rinv[tid] = 0.f;
  if (tid < 68) {
    const int u = halo_u(tid, u0);
    rinv[tid] = (u >= 0 && u < W_) ? (1.f / rsrow[u]) : 0.f;
  }
  // halo validity for the t=4 fragment row of this lane
  const int uh = halo_u(64 + (l15 & 3), u0);
  const bool hok = (uh >= 0 && uh < W_);
  __syncthreads();   // rinv ready

  f32x4 xacc[4] = {};
  float vsum[4] = {};
  const int vq4 = (wv << 4) + (l4 << 2);

  for (int vb = 0; vb < 5; ++vb) {
    const int v0 = vb * 64;
    // K frags from global split planes
    const size_t ka = pbase + (size_t)(v0 + (wv << 4) + l15)*64 + l4*8;
    const s16x8 kh0 = *(const s16x8*)&KHg[ka];
    const s16x8 kh1 = *(const s16x8*)&KHg[ka + 32];
    const s16x8 kl0 = *(const s16x8*)&KLg[ka];
    const s16x8 kl1 = *(const s16x8*)&KLg[ka + 32];

    float P[5][4];
    #pragma unroll
    for (int t = 0; t < 5; ++t) {
      s16x8 qh0, qh1, ql0, ql1;
      if (t < 4) {
        const size_t a = pbase + (size_t)(u0 + t*16 + l15)*64 + l4*8;
        qh0 = *(const s16x8*)&QHg[a];
        qh1 = *(const s16x8*)&QHg[a + 32];
        ql0 = *(const s16x8*)&QLg[a];
        ql1 = *(const s16x8*)&QLg[a + 32];
      } else if (hok) {
        const size_t a = pbase + (size_t)uh*64 + l4*8;
        qh0 = *(const s16x8*)&QHg[a];
        qh1 = *(const s16x8*)&QHg[a + 32];
        ql0 = *(const s16x8*)&QLg[a];
        ql1 = *(const s16x8*)&QLg[a + 32];
      } else {
        s16x8 z = {};
        qh0 = z; qh1 = z; ql0 = z; ql1 = z;
      }
      f32x4 s = {};
      s = __builtin_amdgcn_mfma_f32_16x16x32_bf16(kh0, qh0, s, 0, 0, 0);
      s = __builtin_amdgcn_mfma_f32_16x16x32_bf16(kh1, qh1, s, 0, 0, 0);
      s = __builtin_amdgcn_mfma_f32_16x16x32_bf16(kl0, qh0, s, 0, 0, 0);
      s = __builtin_amdgcn_mfma_f32_16x16x32_bf16(kl1, qh1, s, 0, 0, 0);
      s = __builtin_amdgcn_mfma_f32_16x16x32_bf16(kh0, ql0, s, 0, 0, 0);
      s = __builtin_amdgcn_mfma_f32_16x16x32_bf16(kh1, ql1, s, 0, 0, 0);
      const float ri = rinv[(t < 4) ? (t*16 + l15) : (64 + l15)];
      #pragma unroll
      for (int r = 0; r < 4; ++r) P[t][r] = __expf(s[r]) * ri;
    }
    // write P to fp16 plane: core rows + halo rows
    #pragma unroll
    for (int t = 0; t < 4; ++t) {
      h16x4 hp = {(_Float16)P[t][0], (_Float16)P[t][1], (_Float16)P[t][2], (_Float16)P[t][3]};
      *(h16x4*)&Ph[psw(t*16 + l15, vq4)] = hp;
    }
    if (l15 < 4) {
      h16x4 hp = {(_Float16)P[4][0], (_Float16)P[4][1], (_Float16)P[4][2], (_Float16)P[4][3]};
      *(h16x4*)&Ph[psw(64 + l15, vq4)] = hp;
    }
    __syncthreads();

    // xT: A = Ph rows (u), B = x rows (c) straight from global fp16 plane
    {
      const int ur = (wv << 4) + l15;
      const h16x8 pa0 = *(const h16x8*)&Ph[psw(ur, l4*8)];
      const h16x8 pa1 = *(const h16x8*)&Ph[psw(ur, 32 + l4*8)];
      #pragma unroll
      for (int t = 0; t < 4; ++t) {
        const int crow = t*16 + l15;
        const size_t xa = ((size_t)(b*64 + crow)*H_ + h)*W_ + v0 + l4*8;
        const h16x8 xb0 = *(const h16x8*)&xh[xa];
        const h16x8 xb1 = *(const h16x8*)&xh[xa + 32];
        xacc[t] = __builtin_amdgcn_mfma_f32_16x16x32_f16(pa0, xb0, xacc[t], 0, 0, 0);
        xacc[t] = __builtin_amdgcn_mfma_f32_16x16x32_f16(pa1, xb1, xacc[t], 0, 0, 0);
      }
    }

    // banded V: d=0 from f32 regs, neighbors from fp16 plane
    {
      const float4 cs4 = *(const float4*)&csrow[v0 + vq4];
      const float ci[4] = {1.f/cs4.x, 1.f/cs4.y, 1.f/cs4.z, 1.f/cs4.w};
      #pragma unroll
      for (int t = 0; t < 4; ++t) {
        float w[4] = {P[t][0], P[t][1], P[t][2], P[t][3]};
        #pragma unroll
        for (int d = -2; d <= 2; ++d) {
          if (d == 0) continue;
          const int q = t*16 + l15 + d;
          const int rr = (q < 0) ? (66 + q) : ((q > 63) ? (q + 2) : q);
          const h16x4 pn = *(const h16x4*)&Ph[psw(rr, vq4)];
          w[0] += (float)pn[0]; w[1] += (float)pn[1];
          w[2] += (float)pn[2]; w[3] += (float)pn[3];
        }
        #pragma unroll
        for (int r = 0; r < 4; ++r)
          vsum[t] = fmaf(P[t][r] * ci[r], w[r], vsum[t]);
      }
    }
    __syncthreads();
  }

  // V reduce: over l4 (shfl bits 4,5), then across waves via LDS
  #pragma unroll
  for (int t = 0; t < 4; ++t) {
    float v = vsum[t];
    v += __shfl_xor(v, 16); v += __shfl_xor(v, 32);
    vsum[t] = v;
  }
  if (l4 == 0) {
    #pragma unroll
    for (int t = 0; t < 4; ++t) Vw[(wv << 6) + (t << 4) + l15] = vsum[t];
  }
  __syncthreads();
  if (tid < 64) {
    float v = Vw[tid] + Vw[64+tid] + Vw[128+tid] + Vw[192+tid];
    Vt[tid] = tanhf(5.f * v * rsrow[u0 + tid]);
  }
  __syncthreads();

  // epilogue: lane holds xT[u = wv*16 + l4*4 + r][c = t*16 + l15]
  const int ubu = (wv << 4) + (l4 << 2);
  float tv[4];
  #pragma unroll
  for (int r = 0; r < 4; ++r) tv[r] = Vt[ubu + r];
  #pragma unroll
  for (int t = 0; t < 4; ++t) {
    const int c = (t << 4) + l15;
    const size_t base = rowoff + (size_t)c*HW_ + u0 + ubu;
    const float4 xb4 = *(const float4*)&xblend[base];
    float4 o4;
    o4.x = xb4.x * (1.f - tv[0]) + xacc[t][0] * tv[0];
    o4.y = xb4.y * (1.f - tv[1]) + xacc[t][1] * tv[1];
    o4.z = xb4.z * (1.f - tv[2]) + xacc[t][2] * tv[2];
    o4.w = xb4.w * (1.f - tv[3]) + xacc[t][3] * tv[3];
    *(float4*)&outp[base] = o4;
  }
}

// ---------------------------------------------------------------------------
extern "C" void kernel_launch(void* const* d_in, const int* in_sizes, int n_in,
                              void* d_out, int out_size, void* d_ws, size_t ws_size,
                              hipStream_t stream) {
  const float* x_left  = (const float*)d_in[0];
  const float* x_right = (const float*)d_in[1];
  const float* catL    = (const float*)d_in[2];
  const float* catR    = (const float*)d_in[3];
  const float* bq_w    = (const float*)d_in[4];
  const float* bq_b    = (const float*)d_in[5];
  const float* bs_w    = (const float*)d_in[6];
  const float* bs_b    = (const float*)d_in[7];
  const float* rb_w1   = (const float*)d_in[8];
  const float* rb_b1   = (const float*)d_in[9];
  const float* rb_w2   = (const float*)d_in[10];
  const float* rb_b2   = (const float*)d_in[11];
  const float* gamma   = (const float*)d_in[12];
  const float* beta    = (const float*)d_in[13];

  float* ws = (float*)d_ws;
  size_t off = 0;
  float* WfQ = ws + off; off += WFQ_SZ;
  float* WfK = ws + off; off += WFQ_SZ;
  unsigned short* Wb   = (unsigned short*)(ws + off); off += WB_SZ;
  unsigned short* W2bQ = (unsigned short*)(ws + off); off += W2B_SZ;
  unsigned short* W2bK = (unsigned short*)(ws + off); off += W2B_SZ;
  float* ab  = ws + off; off += AB_SZ;
  float* bfQ = ws + off; off += BF_SZ;
  float* bfK = ws + off; off += BF_SZ;
  float2* pb = (float2*)(ws + off); off += PB_SZ;
  unsigned short* t1   = (unsigned short*)(ws + off); off += T1_SZ;
  unsigned short* catb = (unsigned short*)(ws + off); off += CATB_SZ;
  float* Qb  = ws + off; off += QK_SZ;
  float* Kb  = ws + off; off += QK_SZ;
  float* rsb = ws + off; off += RS_SZ;
  float* csb = ws + off; off += RS_SZ;
  float* csp = ws + off; off += CSP_SZ;

  // aliases: split planes live in catb's space, xh planes in t1's space
  unsigned short* QHg = catb;
  unsigned short* QLg = catb + 6553600;
  unsigned short* KHg = catb + 13107200;
  unsigned short* KLg = catb + 19660800;
  _Float16* xhL = (_Float16*)t1;
  _Float16* xhR = xhL + 6553600;

  wtrans_kernel<<<576, 256, 0, stream>>>(rb_w1, rb_w2, bq_w, bs_w, Wb, WfQ, WfK);
  bnstats1_kernel<<<4096, 256, 0, stream>>>(catL, catR, pb);
  bnstats2_kernel<<<2, 256, 0, stream>>>(pb, gamma, beta, ab);
  prep2_kernel<<<160, 256, 0, stream>>>(bq_w, bs_w, bq_b, bs_b, rb_b2,
                                        WfQ, WfK, W2bQ, W2bK, bfQ, bfK);

  dim3 agrid(HW_/64, 1, 8);
  dim3 cgrid(5, 80, 8);
  // left -> Q
  bnapply_kernel<<<agrid, 256, 0, stream>>>(catL, ab, catb);
  conv1_mfma<<<cgrid, 256, 0, stream>>>(catb, Wb, rb_b1, t1);
  conv2_mfma<<<cgrid, 256, 0, stream>>>(t1, catb, W2bQ, bfQ, Qb);
  // right -> K
  bnapply_kernel<<<agrid, 256, 0, stream>>>(catR, ab + 512, catb);
  conv1_mfma<<<cgrid, 256, 0, stream>>>(catb, Wb, rb_b1, t1);
  conv2_mfma<<<cgrid, 256, 0, stream>>>(t1, catb, W2bK, bfK, Kb);

  rowmean_kernel<<<B_*C0_*H_, 64, 0, stream>>>(Qb);
  rowmean_kernel<<<B_*C0_*H_, 64, 0, stream>>>(Kb);

  // build split planes (overwrites catb space) and fp16 x planes (t1 space)
  qksplit_kernel<<<dim3(5, NROWS_), 256, 0, stream>>>(Qb, QHg, QLg);
  qksplit_kernel<<<dim3(5, NROWS_), 256, 0, stream>>>(Kb, KHg, KLg);
  xcvt_kernel<<<3200, 256, 0, stream>>>(x_left, x_right, xhL, xhR);

  stats_kernel<<<1600, 256, 0, stream>>>(QHg, QLg, KHg, KLg, rsb, csp);
  csreduce_kernel<<<(int)((RS_SZ + 255)/256), 256, 0, stream>>>(csp, csb);

  float* outL = (float*)d_out;
  float* outR = outL + QK_SZ;
  attn_kernel<<<1600, 256, 0, stream>>>(QHg, QLg, KHg, KLg,
                                        rsb, csb, xhR, x_left, outL);
  attn_kernel<<<1600, 256, 0, stream>>>(KHg, KLg, QHg, QLg,
                                        csb, rsb, xhL, x_right, outR);
}

// Round 11
// 595.632 us; speedup vs baseline: 1.5140x; 1.5140x over previous
//
#include <hip/hip_runtime.h>

#define B_    2
#define C0_   64
#define C4_   256
#define H_    160
#define W_    320
#define G_    4
#define HW_   (H_*W_)
#define NROWS_ (B_*H_)      // 320
#define EPS_  1e-5f

typedef float f32x4 __attribute__((ext_vector_type(4)));
typedef short s16x8 __attribute__((ext_vector_type(8)));
typedef _Float16 h16x8 __attribute__((ext_vector_type(8)));
typedef _Float16 h16x4 __attribute__((ext_vector_type(4)));

// workspace sizes (in floats)
#define WFQ_SZ  36864       // f32 [g][tap9][o16][ic64]
#define WB_SZ   73728       // bf16 conv1 weights (147456 shorts)
#define W2B_SZ  20480       // bf16 fused conv2 weights (40960 shorts)
#define AB_SZ   1024
#define BF_SZ   64
#define PB_SZ   8192        // bnstats partials: 4096 float2
#define T1_SZ   13107200    // bf16 t1 [b][g][h][w][ic64]; later: xh fp16 planes
#define CATB_SZ 13107200    // bf16 catb; later: Q/K split planes
#define QK_SZ   ((size_t)B_*C0_*HW_)   // 6553600
#define RS_SZ   ((size_t)NROWS_*W_)    // 102400
#define CSP_SZ  ((size_t)NROWS_*5*W_)  // 512000

__device__ __forceinline__ unsigned f2bf1(float x) {
  unsigned u = __float_as_uint(x);
  return (u + 0x7FFFu + ((u >> 16) & 1u)) >> 16;
}
__device__ __forceinline__ unsigned packbf(float lo, float hi) {
  return f2bf1(lo) | (f2bf1(hi) << 16);
}
// swizzled short-index into a [row][64] 2B plane: XOR 16B-chunk by (row&7)
__device__ __forceinline__ int psw(int r, int c) {
  return (r << 6) + (((c >> 3) ^ (r & 7)) << 3) + (c & 7);
}

// ---------------------------------------------------------------------------
// wtrans: Wb bf16 [g][tap][oc][ic]; WfQ/WfK f32 [g][tap][o16][ic] (proj-folded)
__global__ __launch_bounds__(256) void wtrans_kernel(
    const float* __restrict__ w1, const float* __restrict__ w2,
    const float* __restrict__ bq, const float* __restrict__ bs,
    unsigned short* __restrict__ Wb, float* __restrict__ WfQ, float* __restrict__ WfK) {
  int idx = blockIdx.x * 256 + threadIdx.x;
  if (idx < 147456) {
    int ic = idx & 63, oc = (idx >> 6) & 63, tap = (idx >> 12) % 9, g = idx / 36864;
    float v = w1[((size_t)(g*64 + oc) * 64 + ic) * 9 + tap];
    Wb[idx] = (unsigned short)f2bf1(v);
  }
  if (idx < 36864) {
    int ic = idx & 63, o = (idx >> 6) & 15, tap = (idx >> 10) % 9, g = idx / 9216;
    const float* w2p = w2 + ((size_t)(g*64) * 64 + ic) * 9 + tap;   // + oc*576
    const float* bqp = bq + (size_t)(g*16 + o) * 64;
    const float* bsp = bs + (size_t)(g*16 + o) * 64;
    float sq = 0.f, sk = 0.f;
    for (int oc = 0; oc < 64; ++oc) {
      float wv = w2p[(size_t)oc * 576];
      sq = fmaf(bqp[oc], wv, sq);
      sk = fmaf(bsp[oc], wv, sk);
    }
    WfQ[idx] = sq;
    WfK[idx] = sk;
  }
}

// ---------------------------------------------------------------------------
// bnstats stage 1: per (side, channel, hw-chunk) partial sum/sumsq, float4 loads.
__global__ __launch_bounds__(256) void bnstats1_kernel(
    const float* __restrict__ catL, const float* __restrict__ catR,
    float2* __restrict__ pb) {
  const int bid = blockIdx.x;
  const int sc = bid >> 3, ck = bid & 7;
  const int side = sc >> 8, c = sc & 255;
  const float* base = (side ? catR : catL) + (size_t)c * HW_ + ck * (HW_/8);
  float s = 0.f, s2 = 0.f;
  for (int i = threadIdx.x; i < 1600; i += 256) {
    const float4 v0 = *(const float4*)&base[4*i];
    const float4 v1 = *(const float4*)&base[(size_t)C4_*HW_ + 4*i];
    s  += (v0.x + v0.y) + (v0.z + v0.w) + (v1.x + v1.y) + (v1.z + v1.w);
    float t0 = fmaf(v0.x, v0.x, v0.y*v0.y) + fmaf(v0.z, v0.z, v0.w*v0.w);
    float t1 = fmaf(v1.x, v1.x, v1.y*v1.y) + fmaf(v1.z, v1.z, v1.w*v1.w);
    s2 += t0 + t1;
  }
  #pragma unroll
  for (int o = 32; o; o >>= 1) { s += __shfl_down(s, o); s2 += __shfl_down(s2, o); }
  __shared__ float rs[4], rs2[4];
  const int wid = threadIdx.x >> 6;
  if ((threadIdx.x & 63) == 0) { rs[wid] = s; rs2[wid] = s2; }
  __syncthreads();
  if (threadIdx.x == 0)
    pb[bid] = make_float2(rs[0]+rs[1]+rs[2]+rs[3], rs2[0]+rs2[1]+rs2[2]+rs2[3]);
}

__global__ __launch_bounds__(256) void bnstats2_kernel(
    const float2* __restrict__ pb, const float* __restrict__ gamma,
    const float* __restrict__ beta, float* __restrict__ ab) {
  const int sc = blockIdx.x * 256 + threadIdx.x;
  if (sc >= 512) return;
  const int side = sc >> 8, c = sc & 255;
  float s = 0.f, s2 = 0.f;
  #pragma unroll
  for (int k = 0; k < 8; ++k) {
    const float2 p = pb[sc*8 + k];
    s += p.x; s2 += p.y;
  }
  const float inv_n = 1.f / (float)(2*HW_);
  const float mu  = s * inv_n;
  const float var = s2 * inv_n - mu*mu;
  const float a = gamma[c] * rsqrtf(var + EPS_);
  ab[side*512 + c]       = a;
  ab[side*512 + 256 + c] = beta[c] - mu*a;
}

// ---------------------------------------------------------------------------
// bnapply: catb[b][g][px][ic64] = bf16( a*cat + shift ). One side per launch.
__global__ __launch_bounds__(256) void bnapply_kernel(
    const float* __restrict__ cat, const float* __restrict__ abs_,
    unsigned short* __restrict__ catb) {
  const int z = blockIdx.z;
  const int b = z >> 2, g = z & 3;
  const int tid = threadIdx.x;
  const int px = blockIdx.x * 64 + (tid & 63);
  const int ic0 = (tid >> 6) * 16;
  const float* src = cat + ((size_t)b*C4_ + g*64 + ic0) * HW_ + px;
  const float* abp = abs_ + g*64 + ic0;
  unsigned short* dst = catb + (((size_t)(b*4 + g)*HW_ + px) << 6) + ic0;
  unsigned pk[8];
  #pragma unroll
  for (int j = 0; j < 8; ++j) {
    const float2 a2 = *(const float2*)&abp[2*j];
    const float2 s2 = *(const float2*)&abp[256 + 2*j];
    float v0 = fmaf(a2.x, src[(size_t)(2*j)*HW_],   s2.x);
    float v1 = fmaf(a2.y, src[(size_t)(2*j+1)*HW_], s2.y);
    pk[j] = packbf(v0, v1);
  }
  *(uint4*)&dst[0] = *(uint4*)&pk[0];
  *(uint4*)&dst[8] = *(uint4*)&pk[4];
}

// ---------------------------------------------------------------------------
// prep2: W2bQ/K bf16 [g][tap10][o][ic]; bf[o] = proj_bias + sum_c w*b2_c
__global__ __launch_bounds__(256) void prep2_kernel(
    const float* __restrict__ bq, const float* __restrict__ bs,
    const float* __restrict__ bqb, const float* __restrict__ bsb,
    const float* __restrict__ b2,
    const float* __restrict__ WfQ, const float* __restrict__ WfK,
    unsigned short* __restrict__ W2bQ, unsigned short* __restrict__ W2bK,
    float* __restrict__ bfQ, float* __restrict__ bfK) {
  int idx = blockIdx.x*256 + threadIdx.x;
  if (idx < 40960) {
    int ic = idx & 63, o = (idx >> 6) & 15, tap = (idx >> 10) % 10, g = idx / 10240;
    float vq, vk;
    if (tap < 9) {
      int src = ((g*9 + tap)*16 + o)*64 + ic;
      vq = WfQ[src]; vk = WfK[src];
    } else {
      vq = bq[(size_t)(g*16 + o)*64 + ic];
      vk = bs[(size_t)(g*16 + o)*64 + ic];
    }
    W2bQ[idx] = (unsigned short)f2bf1(vq);
    W2bK[idx] = (unsigned short)f2bf1(vk);
  }
  if (idx < 128) {
    int side = idx >> 6, co = idx & 63, g = co >> 4, o = co & 15;
    const float* w = side ? bs : bq;
    float s = (side ? bsb : bqb)[co];
    for (int c2 = 0; c2 < 64; ++c2) {
      int ch = g*64 + c2;
      s = fmaf(w[(size_t)(g*16 + o)*64 + c2], b2[ch], s);
    }
    (side ? bfK : bfQ)[co] = s;
  }
}

// ---------------------------------------------------------------------------
// conv1 MFMA: t1[b][g][h][w][oc64](bf16) = leaky(gconv3x3(catb) + b1)
__global__ __launch_bounds__(256) void conv1_mfma(
    const unsigned short* __restrict__ catb,
    const unsigned short* __restrict__ Wb, const float* __restrict__ bias,
    unsigned short* __restrict__ t1) {
  const int b = blockIdx.z >> 2, g = blockIdx.z & 3;
  const int h0 = blockIdx.y * 2, w0 = blockIdx.x * 64;
  const int tid = threadIdx.x;
  const int lane = tid & 63, wv = tid >> 6;
  const int m0 = wv * 16;
  const int m = lane & 15, kg = lane >> 4;
  __shared__ short Xs[4*66*72];   // [r4][c66][icpad72]

  const unsigned short* catbg = catb + (((size_t)(b*4 + g)*H_) << 6) * W_;
  for (int u = tid; u < 264*8; u += 256) {
    int rc = u >> 3, j = u & 7;
    int r = rc / 66, c = rc - r*66;
    int gh = h0 - 1 + r, gw = w0 - 1 + c;
    s16x8 v = {};
    if (gh >= 0 && gh < H_ && gw >= 0 && gw < W_)
      v = *(const s16x8*)&catbg[(((size_t)gh*W_ + gw) << 6) + j*8];
    *(s16x8*)&Xs[rc*72 + j*8] = v;
  }

  s16x8 afrag[18];
  #pragma unroll
  for (int s = 0; s < 18; ++s) {
    const int tap = s >> 1, ic0 = (s & 1)*32 + kg*8;
    afrag[s] = *(const s16x8*)&Wb[(((size_t)g*9 + tap)*64 + m0 + m)*64 + ic0];
  }
  __syncthreads();

  f32x4 acc[8] = {};
  #pragma unroll
  for (int s = 0; s < 18; ++s) {
    const int tap = s >> 1, dh = tap / 3, dw = tap - dh*3;
    const int ic0 = (s & 1)*32 + kg*8;
    #pragma unroll
    for (int t = 0; t < 8; ++t) {
      const int px = t*16 + m;
      const int r = px >> 6, wl = px & 63;
      const s16x8 bfrag = *(const s16x8*)&Xs[((r + dh)*66 + wl + dw)*72 + ic0];
      acc[t] = __builtin_amdgcn_mfma_f32_16x16x32_bf16(afrag[s], bfrag, acc[t], 0, 0, 0);
    }
  }

  const int ocq = m0 + kg*4;
  const float4 b4 = *(const float4*)&bias[g*64 + ocq];
  const float bb[4] = {b4.x, b4.y, b4.z, b4.w};
  #pragma unroll
  for (int t = 0; t < 8; ++t) {
    const int px = t*16 + m;
    const int h = h0 + (px >> 6), w = w0 + (px & 63);
    float v[4];
    #pragma unroll
    for (int r = 0; r < 4; ++r) {
      float x = acc[t][r] + bb[r];
      v[r] = (x >= 0.f) ? x : 0.1f * x;
    }
    const size_t base = ((((size_t)(b*4 + g)*H_ + h)*W_ + w) << 6) + ocq;
    uint2 pk; pk.x = packbf(v[0], v[1]); pk.y = packbf(v[2], v[3]);
    *(uint2*)&t1[base] = pk;
  }
}

// ---------------------------------------------------------------------------
// conv2 MFMA + folded 1x1 proj + residual-as-K (residual data = catb)
__global__ __launch_bounds__(256) void conv2_mfma(
    const unsigned short* __restrict__ t1, const unsigned short* __restrict__ catb,
    const unsigned short* __restrict__ W2b,
    const float* __restrict__ bf, float* __restrict__ qout) {
  const int b = blockIdx.z >> 2, g = blockIdx.z & 3;
  const int h0 = blockIdx.y * 2, w0 = blockIdx.x * 64;
  const int tid = threadIdx.x;
  const int lane = tid & 63, wv = tid >> 6;
  const int m = lane & 15, kg = lane >> 4;
  __shared__ short Ys[4*66*72];
  __shared__ short Rs[128*72];

  const unsigned short* t1g = t1 + (((size_t)(b*4 + g)*H_) << 6) * W_;
  const unsigned short* catbg = catb + (((size_t)(b*4 + g)*H_) << 6) * W_;
  for (int u = tid; u < 264*8; u += 256) {
    int rc = u >> 3, j = u & 7;
    int r = rc / 66, c = rc - r*66;
    int gh = h0 - 1 + r, gw = w0 - 1 + c;
    s16x8 v = {};
    if (gh >= 0 && gh < H_ && gw >= 0 && gw < W_)
      v = *(const s16x8*)&t1g[(((size_t)gh*W_ + gw) << 6) + j*8];
    *(s16x8*)&Ys[(rc*72) + j*8] = v;
  }
  for (int u = tid; u < 128*8; u += 256) {
    int px = u >> 3, j = u & 7;
    int gh = h0 + (px >> 6), gw = w0 + (px & 63);
    *(s16x8*)&Rs[px*72 + j*8] =
        *(const s16x8*)&catbg[(((size_t)gh*W_ + gw) << 6) + j*8];
  }

  s16x8 afrag[20];
  #pragma unroll
  for (int s = 0; s < 20; ++s) {
    const int tap = (s < 18) ? (s >> 1) : 9;
    const int ic0 = (s < 18) ? ((s & 1)*32 + kg*8) : ((s - 18)*32 + kg*8);
    afrag[s] = *(const s16x8*)&W2b[(((size_t)g*10 + tap)*16 + m)*64 + ic0];
  }
  __syncthreads();

  f32x4 acc[2] = {};
  #pragma unroll
  for (int s = 0; s < 18; ++s) {
    const int tap = s >> 1, dh = tap / 3, dw = tap - dh*3;
    const int ic0 = (s & 1)*32 + kg*8;
    #pragma unroll
    for (int t = 0; t < 2; ++t) {
      const int px = (wv*2 + t)*16 + m;
      const int r = px >> 6, wl = px & 63;
      const s16x8 bfrag = *(const s16x8*)&Ys[((r + dh)*66 + wl + dw)*72 + ic0];
      acc[t] = __builtin_amdgcn_mfma_f32_16x16x32_bf16(afrag[s], bfrag, acc[t], 0, 0, 0);
    }
  }
  #pragma unroll
  for (int s = 18; s < 20; ++s) {
    const int ic0 = (s - 18)*32 + kg*8;
    #pragma unroll
    for (int t = 0; t < 2; ++t) {
      const int px = (wv*2 + t)*16 + m;
      const s16x8 bfrag = *(const s16x8*)&Rs[px*72 + ic0];
      acc[t] = __builtin_amdgcn_mfma_f32_16x16x32_bf16(afrag[s], bfrag, acc[t], 0, 0, 0);
    }
  }

  const int ocq = kg*4;
  const float4 q4 = *(const float4*)&bf[g*16 + ocq];
  const float qb[4] = {q4.x, q4.y, q4.z, q4.w};
  #pragma unroll
  for (int t = 0; t < 2; ++t) {
    const int px = (wv*2 + t)*16 + m;
    const int h = h0 + (px >> 6), w = w0 + (px & 63);
    #pragma unroll
    for (int r = 0; r < 4; ++r) {
      const int oc = g*16 + ocq + r;
      qout[((size_t)(b*64 + oc)*H_ + h)*W_ + w] = acc[t][r] + qb[r];
    }
  }
}

// ---------------------------------------------------------------------------
__global__ __launch_bounds__(64) void rowmean_kernel(float* __restrict__ q) {
  float* p = q + (size_t)blockIdx.x * W_;
  const int lane = threadIdx.x;
  float v[5]; float s = 0.f;
  #pragma unroll
  for (int k = 0; k < 5; ++k) { v[k] = p[lane + 64*k]; s += v[k]; }
  #pragma unroll
  for (int o = 32; o; o >>= 1) s += __shfl_xor(s, o);
  const float m = s * (1.f/320.f);
  #pragma unroll
  for (int k = 0; k < 5; ++k) p[lane + 64*k] = v[k] - m;
}

// ---------------------------------------------------------------------------
// qksplit: f32 [b][c][h][w] (row-mean'd) -> split bf16 planes [row][u][c]
__global__ __launch_bounds__(256) void qksplit_kernel(
    const float* __restrict__ src,
    unsigned short* __restrict__ dstH, unsigned short* __restrict__ dstL) {
  const int ut = blockIdx.x, row = blockIdx.y;
  const int u0 = ut * 64;
  const int b = row / H_, hh = row - b*H_;
  const int tid = threadIdx.x;
  __shared__ float Tf[64][65];   // [c][u]
  for (int i = tid; i < 1024; i += 256) {
    int c = i >> 4, q = i & 15;
    *(float4*)&Tf[c][4*q] =
        *(const float4*)&src[((size_t)(b*64 + c)*H_ + hh)*W_ + u0 + 4*q];
  }
  __syncthreads();
  for (int i = tid; i < 512; i += 256) {
    int u = i >> 3, j = i & 7;
    unsigned hi[8], lo[8];
    #pragma unroll
    for (int k = 0; k < 8; ++k) {
      float v = Tf[j*8 + k][u];
      unsigned hh32 = f2bf1(v);
      hi[k] = hh32;
      lo[k] = f2bf1(v - __uint_as_float(hh32 << 16));
    }
    unsigned ph[4], pl[4];
    #pragma unroll
    for (int k = 0; k < 4; ++k) {
      ph[k] = hi[2*k] | (hi[2*k+1] << 16);
      pl[k] = lo[2*k] | (lo[2*k+1] << 16);
    }
    const size_t dst = ((size_t)row*320 + u0 + u)*64 + j*8;
    *(uint4*)&dstH[dst] = *(uint4*)&ph[0];
    *(uint4*)&dstL[dst] = *(uint4*)&pl[0];
  }
}

// xcvt: x_left/x_right f32 -> fp16 planes (same [b][c][h][w] layout)
__global__ __launch_bounds__(256) void xcvt_kernel(
    const float* __restrict__ xl, const float* __restrict__ xr,
    _Float16* __restrict__ dl, _Float16* __restrict__ dr) {
  const size_t i8 = ((size_t)blockIdx.x*256 + threadIdx.x) * 8;
  if (i8 >= QK_SZ) return;
  float4 a = *(const float4*)&xl[i8], b4 = *(const float4*)&xl[i8+4];
  h16x8 o = {(_Float16)a.x,(_Float16)a.y,(_Float16)a.z,(_Float16)a.w,
             (_Float16)b4.x,(_Float16)b4.y,(_Float16)b4.z,(_Float16)b4.w};
  *(h16x8*)&dl[i8] = o;
  a = *(const float4*)&xr[i8]; b4 = *(const float4*)&xr[i8+4];
  h16x8 o2 = {(_Float16)a.x,(_Float16)a.y,(_Float16)a.z,(_Float16)a.w,
              (_Float16)b4.x,(_Float16)b4.y,(_Float16)b4.z,(_Float16)b4.w};
  *(h16x8*)&dr[i8] = o2;
}

// ---------------------------------------------------------------------------
// stats: LDS fragment planes, staged via pure 16B copies from global planes.
// XCD-chunked swizzle: all 5 ub-blocks of a row on one XCD (1600 = 8*200).
__global__ __launch_bounds__(256, 4) void stats_kernel(
    const unsigned short* __restrict__ QHg, const unsigned short* __restrict__ QLg,
    const unsigned short* __restrict__ KHg, const unsigned short* __restrict__ KLg,
    float* __restrict__ rsum, float* __restrict__ cspart) {
  const int bid = blockIdx.x;
  const int swz = (bid & 7) * 200 + (bid >> 3);
  const int row = swz / 5, ub = swz - row*5;
  const int u0 = ub * 64;
  const int tid = threadIdx.x;
  const int lane = tid & 63, wv = tid >> 6;
  const int l15 = lane & 15, l4 = lane >> 4;
  __shared__ unsigned short QH[64*64], QL[64*64], KH[64*64], KL[64*64];
  __shared__ float rsw[256];
  const size_t pbase = (size_t)row * 320 * 64;

  // stage Q planes once (pure 16B copies, psw on LDS side)
  for (int i = tid; i < 512; i += 256) {
    int r = i >> 3, j = i & 7;
    const size_t a = pbase + (size_t)(u0 + r)*64 + j*8;
    *(s16x8*)&QH[psw(r, j*8)] = *(const s16x8*)&QHg[a];
    *(s16x8*)&QL[psw(r, j*8)] = *(const s16x8*)&QLg[a];
  }
  float rp[4] = {};
  for (int vb = 0; vb < 5; ++vb) {
    __syncthreads();
    for (int i = tid; i < 512; i += 256) {
      int r = i >> 3, j = i & 7;
      const size_t a = pbase + (size_t)(vb*64 + r)*64 + j*8;
      *(s16x8*)&KH[psw(r, j*8)] = *(const s16x8*)&KHg[a];
      *(s16x8*)&KL[psw(r, j*8)] = *(const s16x8*)&KLg[a];
    }
    __syncthreads();
    const int vr = (wv << 4) + l15;
    const s16x8 kh0 = *(const s16x8*)&KH[psw(vr, l4*8)];
    const s16x8 kh1 = *(const s16x8*)&KH[psw(vr, 32 + l4*8)];
    const s16x8 kl0 = *(const s16x8*)&KL[psw(vr, l4*8)];
    const s16x8 kl1 = *(const s16x8*)&KL[psw(vr, 32 + l4*8)];
    float cp[4] = {};
    #pragma unroll
    for (int t = 0; t < 4; ++t) {
      const int qrow = t*16 + l15;
      const s16x8 qh0 = *(const s16x8*)&QH[psw(qrow, l4*8)];
      const s16x8 qh1 = *(const s16x8*)&QH[psw(qrow, 32 + l4*8)];
      const s16x8 ql0 = *(const s16x8*)&QL[psw(qrow, l4*8)];
      const s16x8 ql1 = *(const s16x8*)&QL[psw(qrow, 32 + l4*8)];
      f32x4 s = {};
      s = __builtin_amdgcn_mfma_f32_16x16x32_bf16(kh0, qh0, s, 0, 0, 0);
      s = __builtin_amdgcn_mfma_f32_16x16x32_bf16(kh1, qh1, s, 0, 0, 0);
      s = __builtin_amdgcn_mfma_f32_16x16x32_bf16(kl0, qh0, s, 0, 0, 0);
      s = __builtin_amdgcn_mfma_f32_16x16x32_bf16(kl1, qh1, s, 0, 0, 0);
      s = __builtin_amdgcn_mfma_f32_16x16x32_bf16(kh0, ql0, s, 0, 0, 0);
      s = __builtin_amdgcn_mfma_f32_16x16x32_bf16(kh1, ql1, s, 0, 0, 0);
      float e0 = __expf(s[0]), e1 = __expf(s[1]), e2 = __expf(s[2]), e3 = __expf(s[3]);
      rp[t] += e0 + e1 + e2 + e3;
      cp[0] += e0; cp[1] += e1; cp[2] += e2; cp[3] += e3;
    }
    #pragma unroll
    for (int r = 0; r < 4; ++r) {
      float v = cp[r];
      v += __shfl_xor(v, 1); v += __shfl_xor(v, 2);
      v += __shfl_xor(v, 4); v += __shfl_xor(v, 8);
      cp[r] = v;
    }
    if (l15 == 0) {
      f32x4 cw = {cp[0], cp[1], cp[2], cp[3]};
      *(f32x4*)&cspart[((size_t)row*5 + ub)*W_ + vb*64 + (wv << 4) + (l4 << 2)] = cw;
    }
  }
  #pragma unroll
  for (int t = 0; t < 4; ++t) {
    float v = rp[t];
    v += __shfl_xor(v, 16); v += __shfl_xor(v, 32);
    rp[t] = v;
  }
  if (l4 == 0) {
    #pragma unroll
    for (int t = 0; t < 4; ++t) rsw[(wv << 6) + (t << 4) + l15] = rp[t];
  }
  __syncthreads();
  if (tid < 64)
    rsum[(size_t)row*W_ + u0 + tid] = rsw[tid] + rsw[64+tid] + rsw[128+tid] + rsw[192+tid];
}

__global__ __launch_bounds__(256) void csreduce_kernel(
    const float* __restrict__ csp, float* __restrict__ csum) {
  int idx = blockIdx.x*256 + threadIdx.x;
  if (idx >= (int)RS_SZ) return;
  int row = idx / W_, v = idx - row*W_;
  float s = 0.f;
  #pragma unroll
  for (int ub = 0; ub < 5; ++ub) s += csp[((size_t)row*5 + ub)*W_ + v];
  csum[idx] = s;
}

// ---------------------------------------------------------------------------
__device__ __forceinline__ int halo_u(int k, int u0) {
  if (k < 64) return u0 + k;
  return (k == 64) ? (u0-2) : (k == 65) ? (u0-1) : (k == 66) ? (u0+64) : (u0+65);
}

// attn: round-8 LDS-plane structure, staged via pure 16B copies from the
// precomputed global split planes. XCD-chunked swizzle.
__global__ __launch_bounds__(256, 3) void attn_kernel(
    const unsigned short* __restrict__ QHg, const unsigned short* __restrict__ QLg,
    const unsigned short* __restrict__ KHg, const unsigned short* __restrict__ KLg,
    const float* __restrict__ rsump, const float* __restrict__ csump,
    const _Float16* __restrict__ xh, const float* __restrict__ xblend,
    float* __restrict__ outp) {
  const int bid = blockIdx.x;
  const int swz = (bid & 7) * 200 + (bid >> 3);
  const int row = swz / 5, ub = swz - row*5;
  const int b = row / H_, h = row - b*H_;
  const int u0 = ub * 64;
  const int tid = threadIdx.x;
  const int lane = tid & 63, wv = tid >> 6;
  const int l15 = lane & 15, l4 = lane >> 4;

  __shared__ unsigned short QH[68*64], QL[68*64];   // Q split [u 0..67][c]
  __shared__ unsigned short KH[64*64], KL[64*64];   // K split [v][c]
  __shared__ _Float16 Xh[64*64];                    // x fp16 [c][v]
  __shared__ _Float16 Ph[68*64];                    // P fp16 [u 0..67][v]
  __shared__ float rinv[80];                        // 68..79 = 0
  __shared__ float Vw[256], Vt[64];

  const size_t rowoff = (size_t)b*C0_*HW_ + (size_t)h*W_;
  const size_t pbase = (size_t)row * 320 * 64;
  const float* rsrow = rsump + (size_t)row*W_;
  const float* csrow = csump + (size_t)row*W_;

  if (tid < 80) rinv[tid] = 0.f;
  if (tid < 68) {
    const int u = halo_u(tid, u0);
    rinv[tid] = (u >= 0 && u < W_) ? (1.f / rsrow[u]) : 0.f;
  }
  // Q staging once: 68 rows x 8 chunks per plane, pure 16B copies
  for (int i = tid; i < 544; i += 256) {
    int r = i >> 3, j = i & 7;
    int u = halo_u(r, u0);
    s16x8 vh = {}, vl = {};
    if (u >= 0 && u < W_) {
      const size_t a = pbase + (size_t)u*64 + j*8;
      vh = *(const s16x8*)&QHg[a];
      vl = *(const s16x8*)&QLg[a];
    }
    *(s16x8*)&QH[psw(r, j*8)] = vh;
    *(s16x8*)&QL[psw(r, j*8)] = vl;
  }

  f32x4 xacc[4] = {};
  float vsum[4] = {};
  const int vq4 = (wv << 4) + (l4 << 2);

  for (int vb = 0; vb < 5; ++vb) {
    const int v0 = vb * 64;
    __syncthreads();
    // stage K planes + x plane (16B copies)
    for (int i = tid; i < 512; i += 256) {
      int r = i >> 3, j = i & 7;
      const size_t a = pbase + (size_t)(v0 + r)*64 + j*8;
      *(s16x8*)&KH[psw(r, j*8)] = *(const s16x8*)&KHg[a];
      *(s16x8*)&KL[psw(r, j*8)] = *(const s16x8*)&KLg[a];
    }
    for (int i = tid; i < 512; i += 256) {
      int c = i >> 3, j = i & 7;
      const size_t xa = ((size_t)(b*64 + c)*H_ + h)*W_ + v0 + j*8;
      *(h16x8*)&Xh[psw(c, j*8)] = *(const h16x8*)&xh[xa];
    }
    __syncthreads();

    // ---- S phase: A = K rows (m = v), B = Q rows (n = u)
    const int vr = (wv << 4) + l15;
    const s16x8 kh0 = *(const s16x8*)&KH[psw(vr, l4*8)];
    const s16x8 kh1 = *(const s16x8*)&KH[psw(vr, 32 + l4*8)];
    const s16x8 kl0 = *(const s16x8*)&KL[psw(vr, l4*8)];
    const s16x8 kl1 = *(const s16x8*)&KL[psw(vr, 32 + l4*8)];
    float P[5][4];
    #pragma unroll
    for (int t = 0; t < 5; ++t) {
      const int qrow = (t < 4) ? (t*16 + l15) : (64 + (l15 & 3));
      const s16x8 qh0 = *(const s16x8*)&QH[psw(qrow, l4*8)];
      const s16x8 qh1 = *(const s16x8*)&QH[psw(qrow, 32 + l4*8)];
      const s16x8 ql0 = *(const s16x8*)&QL[psw(qrow, l4*8)];
      const s16x8 ql1 = *(const s16x8*)&QL[psw(qrow, 32 + l4*8)];
      f32x4 s = {};
      s = __builtin_amdgcn_mfma_f32_16x16x32_bf16(kh0, qh0, s, 0, 0, 0);
      s = __builtin_amdgcn_mfma_f32_16x16x32_bf16(kh1, qh1, s, 0, 0, 0);
      s = __builtin_amdgcn_mfma_f32_16x16x32_bf16(kl0, qh0, s, 0, 0, 0);
      s = __builtin_amdgcn_mfma_f32_16x16x32_bf16(kl1, qh1, s, 0, 0, 0);
      s = __builtin_amdgcn_mfma_f32_16x16x32_bf16(kh0, ql0, s, 0, 0, 0);
      s = __builtin_amdgcn_mfma_f32_16x16x32_bf16(kh1, ql1, s, 0, 0, 0);
      const float ri = rinv[(t < 4) ? (t*16 + l15) : (64 + l15)];   // 0 for pad/OOB
      #pragma unroll
      for (int r = 0; r < 4; ++r) P[t][r] = __expf(s[r]) * ri;
    }
    // write P to fp16 plane: core rows + halo rows
    #pragma unroll
    for (int t = 0; t < 4; ++t) {
      h16x4 hp = {(_Float16)P[t][0], (_Float16)P[t][1], (_Float16)P[t][2], (_Float16)P[t][3]};
      *(h16x4*)&Ph[psw(t*16 + l15, vq4)] = hp;
    }
    if (l15 < 4) {
      h16x4 hp = {(_Float16)P[4][0], (_Float16)P[4][1], (_Float16)P[4][2], (_Float16)P[4][3]};
      *(h16x4*)&Ph[psw(64 + l15, vq4)] = hp;
    }
    __syncthreads();

    // ---- xT phase: A = P rows (m = u), B = x rows (n = c)
    {
      const int ur = (wv << 4) + l15;
      const h16x8 pa0 = *(const h16x8*)&Ph[psw(ur, l4*8)];
      const h16x8 pa1 = *(const h16x8*)&Ph[psw(ur, 32 + l4*8)];
      #pragma unroll
      for (int t = 0; t < 4; ++t) {
        const int crow = t*16 + l15;
        const h16x8 xb0 = *(const h16x8*)&Xh[psw(crow, l4*8)];
        const h16x8 xb1 = *(const h16x8*)&Xh[psw(crow, 32 + l4*8)];
        xacc[t] = __builtin_amdgcn_mfma_f32_16x16x32_f16(pa0, xb0, xacc[t], 0, 0, 0);
        xacc[t] = __builtin_amdgcn_mfma_f32_16x16x32_f16(pa1, xb1, xacc[t], 0, 0, 0);
      }
    }

    // ---- banded V: d=0 from f32 regs, neighbors from fp16 plane
    {
      const float4 cs4 = *(const float4*)&csrow[v0 + vq4];
      const float ci[4] = {1.f/cs4.x, 1.f/cs4.y, 1.f/cs4.z, 1.f/cs4.w};
      #pragma unroll
      for (int t = 0; t < 4; ++t) {
        float w[4] = {P[t][0], P[t][1], P[t][2], P[t][3]};
        #pragma unroll
        for (int d = -2; d <= 2; ++d) {
          if (d == 0) continue;
          const int q = t*16 + l15 + d;
          const int rr = (q < 0) ? (66 + q) : ((q > 63) ? (q + 2) : q);
          const h16x4 pn = *(const h16x4*)&Ph[psw(rr, vq4)];
          w[0] += (float)pn[0]; w[1] += (float)pn[1];
          w[2] += (float)pn[2]; w[3] += (float)pn[3];
        }
        #pragma unroll
        for (int r = 0; r < 4; ++r)
          vsum[t] = fmaf(P[t][r] * ci[r], w[r], vsum[t]);
      }
    }
  }

  // V reduce: over l4 (shfl bits 4,5), then across waves via LDS
  #pragma unroll
  for (int t = 0; t < 4; ++t) {
    float v = vsum[t];
    v += __shfl_xor(v, 16); v += __shfl_xor(v, 32);
    vsum[t] = v;
  }
  if (l4 == 0) {
    #pragma unroll
    for (int t = 0; t < 4; ++t) Vw[(wv << 6) + (t << 4) + l15] = vsum[t];
  }
  __syncthreads();
  if (tid < 64) {
    float v = Vw[tid] + Vw[64+tid] + Vw[128+tid] + Vw[192+tid];
    Vt[tid] = tanhf(5.f * v * rsrow[u0 + tid]);
  }
  __syncthreads();

  // epilogue: lane holds xT[u = wv*16 + l4*4 + r][c = t*16 + l15]
  const int ubu = (wv << 4) + (l4 << 2);
  float tv[4];
  #pragma unroll
  for (int r = 0; r < 4; ++r) tv[r] = Vt[ubu + r];
  #pragma unroll
  for (int t = 0; t < 4; ++t) {
    const int c = (t << 4) + l15;
    const size_t base = rowoff + (size_t)c*HW_ + u0 + ubu;
    const float4 xb4 = *(const float4*)&xblend[base];
    float4 o4;
    o4.x = xb4.x * (1.f - tv[0]) + xacc[t][0] * tv[0];
    o4.y = xb4.y * (1.f - tv[1]) + xacc[t][1] * tv[1];
    o4.z = xb4.z * (1.f - tv[2]) + xacc[t][2] * tv[2];
    o4.w = xb4.w * (1.f - tv[3]) + xacc[t][3] * tv[3];
    *(float4*)&outp[base] = o4;
  }
}

// ---------------------------------------------------------------------------
extern "C" void kernel_launch(void* const* d_in, const int* in_sizes, int n_in,
                              void* d_out, int out_size, void* d_ws, size_t ws_size,
                              hipStream_t stream) {
  const float* x_left  = (const float*)d_in[0];
  const float* x_right = (const float*)d_in[1];
  const float* catL    = (const float*)d_in[2];
  const float* catR    = (const float*)d_in[3];
  const float* bq_w    = (const float*)d_in[4];
  const float* bq_b    = (const float*)d_in[5];
  const float* bs_w    = (const float*)d_in[6];
  const float* bs_b    = (const float*)d_in[7];
  const float* rb_w1   = (const float*)d_in[8];
  const float* rb_b1   = (const float*)d_in[9];
  const float* rb_w2   = (const float*)d_in[10];
  const float* rb_b2   = (const float*)d_in[11];
  const float* gamma   = (const float*)d_in[12];
  const float* beta    = (const float*)d_in[13];

  float* ws = (float*)d_ws;
  size_t off = 0;
  float* WfQ = ws + off; off += WFQ_SZ;
  float* WfK = ws + off; off += WFQ_SZ;
  unsigned short* Wb   = (unsigned short*)(ws + off); off += WB_SZ;
  unsigned short* W2bQ = (unsigned short*)(ws + off); off += W2B_SZ;
  unsigned short* W2bK = (unsigned short*)(ws + off); off += W2B_SZ;
  float* ab  = ws + off; off += AB_SZ;
  float* bfQ = ws + off; off += BF_SZ;
  float* bfK = ws + off; off += BF_SZ;
  float2* pb = (float2*)(ws + off); off += PB_SZ;
  unsigned short* t1   = (unsigned short*)(ws + off); off += T1_SZ;
  unsigned short* catb = (unsigned short*)(ws + off); off += CATB_SZ;
  float* Qb  = ws + off; off += QK_SZ;
  float* Kb  = ws + off; off += QK_SZ;
  float* rsb = ws + off; off += RS_SZ;
  float* csb = ws + off; off += RS_SZ;
  float* csp = ws + off; off += CSP_SZ;

  // aliases: split planes live in catb's space, xh planes in t1's space
  unsigned short* QHg = catb;
  unsigned short* QLg = catb + 6553600;
  unsigned short* KHg = catb + 13107200;
  unsigned short* KLg = catb + 19660800;
  _Float16* xhL = (_Float16*)t1;
  _Float16* xhR = xhL + 6553600;

  wtrans_kernel<<<576, 256, 0, stream>>>(rb_w1, rb_w2, bq_w, bs_w, Wb, WfQ, WfK);
  bnstats1_kernel<<<4096, 256, 0, stream>>>(catL, catR, pb);
  bnstats2_kernel<<<2, 256, 0, stream>>>(pb, gamma, beta, ab);
  prep2_kernel<<<160, 256, 0, stream>>>(bq_w, bs_w, bq_b, bs_b, rb_b2,
                                        WfQ, WfK, W2bQ, W2bK, bfQ, bfK);

  dim3 agrid(HW_/64, 1, 8);
  dim3 cgrid(5, 80, 8);
  // left -> Q
  bnapply_kernel<<<agrid, 256, 0, stream>>>(catL, ab, catb);
  conv1_mfma<<<cgrid, 256, 0, stream>>>(catb, Wb, rb_b1, t1);
  conv2_mfma<<<cgrid, 256, 0, stream>>>(t1, catb, W2bQ, bfQ, Qb);
  // right -> K
  bnapply_kernel<<<agrid, 256, 0, stream>>>(catR, ab + 512, catb);
  conv1_mfma<<<cgrid, 256, 0, stream>>>(catb, Wb, rb_b1, t1);
  conv2_mfma<<<cgrid, 256, 0, stream>>>(t1, catb, W2bK, bfK, Kb);

  rowmean_kernel<<<B_*C0_*H_, 64, 0, stream>>>(Qb);
  rowmean_kernel<<<B_*C0_*H_, 64, 0, stream>>>(Kb);

  // build split planes (overwrites catb space) and fp16 x planes (t1 space)
  qksplit_kernel<<<dim3(5, NROWS_), 256, 0, stream>>>(Qb, QHg, QLg);
  qksplit_kernel<<<dim3(5, NROWS_), 256, 0, stream>>>(Kb, KHg, KLg);
  xcvt_kernel<<<3200, 256, 0, stream>>>(x_left, x_right, xhL, xhR);

  stats_kernel<<<1600, 256, 0, stream>>>(QHg, QLg, KHg, KLg, rsb, csp);
  csreduce_kernel<<<(int)((RS_SZ + 255)/256), 256, 0, stream>>>(csp, csb);

  float* outL = (float*)d_out;
  float* outR = outL + QK_SZ;
  attn_kernel<<<1600, 256, 0, stream>>>(QHg, QLg, KHg, KLg,
                                        rsb, csb, xhR, x_left, outL);
  attn_kernel<<<1600, 256, 0, stream>>>(KHg, KLg, QHg, QLg,
                                        csb, rsb, xhL, x_right, outR);
}

// Round 12
// 595.161 us; speedup vs baseline: 1.5152x; 1.0008x over previous
//
#include <hip/hip_runtime.h>

#define B_    2
#define C0_   64
#define C4_   256
#define H_    160
#define W_    320
#define G_    4
#define HW_   (H_*W_)
#define NROWS_ (B_*H_)      // 320
#define EPS_  1e-5f

typedef float f32x4 __attribute__((ext_vector_type(4)));
typedef short s16x8 __attribute__((ext_vector_type(8)));
typedef _Float16 h16x8 __attribute__((ext_vector_type(8)));
typedef _Float16 h16x4 __attribute__((ext_vector_type(4)));

// workspace sizes (in floats)
#define WFQ_SZ  36864       // f32 [g][tap9][o16][ic64]
#define WB_SZ   73728       // bf16 conv1 weights (147456 shorts)
#define W2B_SZ  20480       // bf16 fused conv2 weights (40960 shorts)
#define AB_SZ   1024
#define BF_SZ   64
#define PB_SZ   8192        // bnstats partials: 4096 float2
#define T1_SZ   13107200    // bf16 t1 [b][g][h][w][ic64]; later: xh fp16 planes
#define CATB_SZ 13107200    // bf16 catb; later: Q/K split planes
#define QK_SZ   ((size_t)B_*C0_*HW_)   // 6553600
#define RS_SZ   ((size_t)NROWS_*W_)    // 102400
#define CSP_SZ  ((size_t)NROWS_*5*W_)  // 512000

__device__ __forceinline__ unsigned f2bf1(float x) {
  unsigned u = __float_as_uint(x);
  return (u + 0x7FFFu + ((u >> 16) & 1u)) >> 16;
}
__device__ __forceinline__ unsigned packbf(float lo, float hi) {
  return f2bf1(lo) | (f2bf1(hi) << 16);
}
// swizzled short-index into a [row][64] 2B plane: XOR 16B-chunk by (row&7)
__device__ __forceinline__ int psw(int r, int c) {
  return (r << 6) + (((c >> 3) ^ (r & 7)) << 3) + (c & 7);
}

// ---------------------------------------------------------------------------
// wtrans: Wb bf16 [g][tap][oc][ic]; WfQ/WfK f32 [g][tap][o16][ic] (proj-folded)
__global__ __launch_bounds__(256) void wtrans_kernel(
    const float* __restrict__ w1, const float* __restrict__ w2,
    const float* __restrict__ bq, const float* __restrict__ bs,
    unsigned short* __restrict__ Wb, float* __restrict__ WfQ, float* __restrict__ WfK) {
  int idx = blockIdx.x * 256 + threadIdx.x;
  if (idx < 147456) {
    int ic = idx & 63, oc = (idx >> 6) & 63, tap = (idx >> 12) % 9, g = idx / 36864;
    float v = w1[((size_t)(g*64 + oc) * 64 + ic) * 9 + tap];
    Wb[idx] = (unsigned short)f2bf1(v);
  }
  if (idx < 36864) {
    int ic = idx & 63, o = (idx >> 6) & 15, tap = (idx >> 10) % 9, g = idx / 9216;
    const float* w2p = w2 + ((size_t)(g*64) * 64 + ic) * 9 + tap;   // + oc*576
    const float* bqp = bq + (size_t)(g*16 + o) * 64;
    const float* bsp = bs + (size_t)(g*16 + o) * 64;
    float sq = 0.f, sk = 0.f;
    for (int oc = 0; oc < 64; ++oc) {
      float wv = w2p[(size_t)oc * 576];
      sq = fmaf(bqp[oc], wv, sq);
      sk = fmaf(bsp[oc], wv, sk);
    }
    WfQ[idx] = sq;
    WfK[idx] = sk;
  }
}

// ---------------------------------------------------------------------------
// bnstats stage 1: per (side, channel, hw-chunk) partial sum/sumsq.
// 320 threads: exactly 5 float4/thread/plane -> fully unrolled, 10 loads in
// flight per thread (MLP 10 vs old 2).
__global__ __launch_bounds__(320) void bnstats1_kernel(
    const float* __restrict__ catL, const float* __restrict__ catR,
    float2* __restrict__ pb) {
  const int bid = blockIdx.x;
  const int sc = bid >> 3, ck = bid & 7;
  const int side = sc >> 8, c = sc & 255;
  const float* p0 = (side ? catR : catL) + (size_t)c * HW_ + ck * (HW_/8);
  const float* p1 = p0 + (size_t)C4_*HW_;
  const int t = threadIdx.x;
  float4 va[10];
  #pragma unroll
  for (int k = 0; k < 5; ++k) {
    va[k]     = *(const float4*)&p0[4*(t + 320*k)];
    va[5 + k] = *(const float4*)&p1[4*(t + 320*k)];
  }
  float s = 0.f, s2 = 0.f;
  #pragma unroll
  for (int k = 0; k < 10; ++k) {
    s  += (va[k].x + va[k].y) + (va[k].z + va[k].w);
    s2 += fmaf(va[k].x, va[k].x, va[k].y*va[k].y)
        + fmaf(va[k].z, va[k].z, va[k].w*va[k].w);
  }
  #pragma unroll
  for (int o = 32; o; o >>= 1) { s += __shfl_down(s, o); s2 += __shfl_down(s2, o); }
  __shared__ float rs[5], rs2[5];
  const int wid = t >> 6;
  if ((t & 63) == 0) { rs[wid] = s; rs2[wid] = s2; }
  __syncthreads();
  if (t == 0) {
    pb[bid] = make_float2(rs[0]+rs[1]+rs[2]+rs[3]+rs[4],
                          rs2[0]+rs2[1]+rs2[2]+rs2[3]+rs2[4]);
  }
}

__global__ __launch_bounds__(256) void bnstats2_kernel(
    const float2* __restrict__ pb, const float* __restrict__ gamma,
    const float* __restrict__ beta, float* __restrict__ ab) {
  const int sc = blockIdx.x * 256 + threadIdx.x;
  if (sc >= 512) return;
  const int side = sc >> 8, c = sc & 255;
  float s = 0.f, s2 = 0.f;
  #pragma unroll
  for (int k = 0; k < 8; ++k) {
    const float2 p = pb[sc*8 + k];
    s += p.x; s2 += p.y;
  }
  const float inv_n = 1.f / (float)(2*HW_);
  const float mu  = s * inv_n;
  const float var = s2 * inv_n - mu*mu;
  const float a = gamma[c] * rsqrtf(var + EPS_);
  ab[side*512 + c]       = a;
  ab[side*512 + 256 + c] = beta[c] - mu*a;
}

// ---------------------------------------------------------------------------
// bnapply: catb[b][g][px][ic64] = bf16( a*cat + shift ). One side per launch.
__global__ __launch_bounds__(256) void bnapply_kernel(
    const float* __restrict__ cat, const float* __restrict__ abs_,
    unsigned short* __restrict__ catb) {
  const int z = blockIdx.z;
  const int b = z >> 2, g = z & 3;
  const int tid = threadIdx.x;
  const int px = blockIdx.x * 64 + (tid & 63);
  const int ic0 = (tid >> 6) * 16;
  const float* src = cat + ((size_t)b*C4_ + g*64 + ic0) * HW_ + px;
  const float* abp = abs_ + g*64 + ic0;
  unsigned short* dst = catb + (((size_t)(b*4 + g)*HW_ + px) << 6) + ic0;
  unsigned pk[8];
  #pragma unroll
  for (int j = 0; j < 8; ++j) {
    const float2 a2 = *(const float2*)&abp[2*j];
    const float2 s2 = *(const float2*)&abp[256 + 2*j];
    float v0 = fmaf(a2.x, src[(size_t)(2*j)*HW_],   s2.x);
    float v1 = fmaf(a2.y, src[(size_t)(2*j+1)*HW_], s2.y);
    pk[j] = packbf(v0, v1);
  }
  *(uint4*)&dst[0] = *(uint4*)&pk[0];
  *(uint4*)&dst[8] = *(uint4*)&pk[4];
}

// ---------------------------------------------------------------------------
// prep2: W2bQ/K bf16 [g][tap10][o][ic]; bf[o] = proj_bias + sum_c w*b2_c
__global__ __launch_bounds__(256) void prep2_kernel(
    const float* __restrict__ bq, const float* __restrict__ bs,
    const float* __restrict__ bqb, const float* __restrict__ bsb,
    const float* __restrict__ b2,
    const float* __restrict__ WfQ, const float* __restrict__ WfK,
    unsigned short* __restrict__ W2bQ, unsigned short* __restrict__ W2bK,
    float* __restrict__ bfQ, float* __restrict__ bfK) {
  int idx = blockIdx.x*256 + threadIdx.x;
  if (idx < 40960) {
    int ic = idx & 63, o = (idx >> 6) & 15, tap = (idx >> 10) % 10, g = idx / 10240;
    float vq, vk;
    if (tap < 9) {
      int src = ((g*9 + tap)*16 + o)*64 + ic;
      vq = WfQ[src]; vk = WfK[src];
    } else {
      vq = bq[(size_t)(g*16 + o)*64 + ic];
      vk = bs[(size_t)(g*16 + o)*64 + ic];
    }
    W2bQ[idx] = (unsigned short)f2bf1(vq);
    W2bK[idx] = (unsigned short)f2bf1(vk);
  }
  if (idx < 128) {
    int side = idx >> 6, co = idx & 63, g = co >> 4, o = co & 15;
    const float* w = side ? bs : bq;
    float s = (side ? bsb : bqb)[co];
    for (int c2 = 0; c2 < 64; ++c2) {
      int ch = g*64 + c2;
      s = fmaf(w[(size_t)(g*16 + o)*64 + c2], b2[ch], s);
    }
    (side ? bfK : bfQ)[co] = s;
  }
}

// ---------------------------------------------------------------------------
// conv1 MFMA: t1[b][g][h][w][oc64](bf16) = leaky(gconv3x3(catb) + b1)
__global__ __launch_bounds__(256) void conv1_mfma(
    const unsigned short* __restrict__ catb,
    const unsigned short* __restrict__ Wb, const float* __restrict__ bias,
    unsigned short* __restrict__ t1) {
  const int b = blockIdx.z >> 2, g = blockIdx.z & 3;
  const int h0 = blockIdx.y * 2, w0 = blockIdx.x * 64;
  const int tid = threadIdx.x;
  const int lane = tid & 63, wv = tid >> 6;
  const int m0 = wv * 16;
  const int m = lane & 15, kg = lane >> 4;
  __shared__ short Xs[4*66*72];   // [r4][c66][icpad72]

  const unsigned short* catbg = catb + (((size_t)(b*4 + g)*H_) << 6) * W_;
  for (int u = tid; u < 264*8; u += 256) {
    int rc = u >> 3, j = u & 7;
    int r = rc / 66, c = rc - r*66;
    int gh = h0 - 1 + r, gw = w0 - 1 + c;
    s16x8 v = {};
    if (gh >= 0 && gh < H_ && gw >= 0 && gw < W_)
      v = *(const s16x8*)&catbg[(((size_t)gh*W_ + gw) << 6) + j*8];
    *(s16x8*)&Xs[rc*72 + j*8] = v;
  }

  s16x8 afrag[18];
  #pragma unroll
  for (int s = 0; s < 18; ++s) {
    const int tap = s >> 1, ic0 = (s & 1)*32 + kg*8;
    afrag[s] = *(const s16x8*)&Wb[(((size_t)g*9 + tap)*64 + m0 + m)*64 + ic0];
  }
  __syncthreads();

  f32x4 acc[8] = {};
  #pragma unroll
  for (int s = 0; s < 18; ++s) {
    const int tap = s >> 1, dh = tap / 3, dw = tap - dh*3;
    const int ic0 = (s & 1)*32 + kg*8;
    #pragma unroll
    for (int t = 0; t < 8; ++t) {
      const int px = t*16 + m;
      const int r = px >> 6, wl = px & 63;
      const s16x8 bfrag = *(const s16x8*)&Xs[((r + dh)*66 + wl + dw)*72 + ic0];
      acc[t] = __builtin_amdgcn_mfma_f32_16x16x32_bf16(afrag[s], bfrag, acc[t], 0, 0, 0);
    }
  }

  const int ocq = m0 + kg*4;
  const float4 b4 = *(const float4*)&bias[g*64 + ocq];
  const float bb[4] = {b4.x, b4.y, b4.z, b4.w};
  #pragma unroll
  for (int t = 0; t < 8; ++t) {
    const int px = t*16 + m;
    const int h = h0 + (px >> 6), w = w0 + (px & 63);
    float v[4];
    #pragma unroll
    for (int r = 0; r < 4; ++r) {
      float x = acc[t][r] + bb[r];
      v[r] = (x >= 0.f) ? x : 0.1f * x;
    }
    const size_t base = ((((size_t)(b*4 + g)*H_ + h)*W_ + w) << 6) + ocq;
    uint2 pk; pk.x = packbf(v[0], v[1]); pk.y = packbf(v[2], v[3]);
    *(uint2*)&t1[base] = pk;
  }
}

// ---------------------------------------------------------------------------
// conv2 MFMA + folded 1x1 proj + residual-as-K (residual data = catb)
__global__ __launch_bounds__(256) void conv2_mfma(
    const unsigned short* __restrict__ t1, const unsigned short* __restrict__ catb,
    const unsigned short* __restrict__ W2b,
    const float* __restrict__ bf, float* __restrict__ qout) {
  const int b = blockIdx.z >> 2, g = blockIdx.z & 3;
  const int h0 = blockIdx.y * 2, w0 = blockIdx.x * 64;
  const int tid = threadIdx.x;
  const int lane = tid & 63, wv = tid >> 6;
  const int m = lane & 15, kg = lane >> 4;
  __shared__ short Ys[4*66*72];
  __shared__ short Rs[128*72];

  const unsigned short* t1g = t1 + (((size_t)(b*4 + g)*H_) << 6) * W_;
  const unsigned short* catbg = catb + (((size_t)(b*4 + g)*H_) << 6) * W_;
  for (int u = tid; u < 264*8; u += 256) {
    int rc = u >> 3, j = u & 7;
    int r = rc / 66, c = rc - r*66;
    int gh = h0 - 1 + r, gw = w0 - 1 + c;
    s16x8 v = {};
    if (gh >= 0 && gh < H_ && gw >= 0 && gw < W_)
      v = *(const s16x8*)&t1g[(((size_t)gh*W_ + gw) << 6) + j*8];
    *(s16x8*)&Ys[(rc*72) + j*8] = v;
  }
  for (int u = tid; u < 128*8; u += 256) {
    int px = u >> 3, j = u & 7;
    int gh = h0 + (px >> 6), gw = w0 + (px & 63);
    *(s16x8*)&Rs[px*72 + j*8] =
        *(const s16x8*)&catbg[(((size_t)gh*W_ + gw) << 6) + j*8];
  }

  s16x8 afrag[20];
  #pragma unroll
  for (int s = 0; s < 20; ++s) {
    const int tap = (s < 18) ? (s >> 1) : 9;
    const int ic0 = (s < 18) ? ((s & 1)*32 + kg*8) : ((s - 18)*32 + kg*8);
    afrag[s] = *(const s16x8*)&W2b[(((size_t)g*10 + tap)*16 + m)*64 + ic0];
  }
  __syncthreads();

  f32x4 acc[2] = {};
  #pragma unroll
  for (int s = 0; s < 18; ++s) {
    const int tap = s >> 1, dh = tap / 3, dw = tap - dh*3;
    const int ic0 = (s & 1)*32 + kg*8;
    #pragma unroll
    for (int t = 0; t < 2; ++t) {
      const int px = (wv*2 + t)*16 + m;
      const int r = px >> 6, wl = px & 63;
      const s16x8 bfrag = *(const s16x8*)&Ys[((r + dh)*66 + wl + dw)*72 + ic0];
      acc[t] = __builtin_amdgcn_mfma_f32_16x16x32_bf16(afrag[s], bfrag, acc[t], 0, 0, 0);
    }
  }
  #pragma unroll
  for (int s = 18; s < 20; ++s) {
    const int ic0 = (s - 18)*32 + kg*8;
    #pragma unroll
    for (int t = 0; t < 2; ++t) {
      const int px = (wv*2 + t)*16 + m;
      const s16x8 bfrag = *(const s16x8*)&Rs[px*72 + ic0];
      acc[t] = __builtin_amdgcn_mfma_f32_16x16x32_bf16(afrag[s], bfrag, acc[t], 0, 0, 0);
    }
  }

  const int ocq = kg*4;
  const float4 q4 = *(const float4*)&bf[g*16 + ocq];
  const float qb[4] = {q4.x, q4.y, q4.z, q4.w};
  #pragma unroll
  for (int t = 0; t < 2; ++t) {
    const int px = (wv*2 + t)*16 + m;
    const int h = h0 + (px >> 6), w = w0 + (px & 63);
    #pragma unroll
    for (int r = 0; r < 4; ++r) {
      const int oc = g*16 + ocq + r;
      qout[((size_t)(b*64 + oc)*H_ + h)*W_ + w] = acc[t][r] + qb[r];
    }
  }
}

// ---------------------------------------------------------------------------
__global__ __launch_bounds__(64) void rowmean_kernel(float* __restrict__ q) {
  float* p = q + (size_t)blockIdx.x * W_;
  const int lane = threadIdx.x;
  float v[5]; float s = 0.f;
  #pragma unroll
  for (int k = 0; k < 5; ++k) { v[k] = p[lane + 64*k]; s += v[k]; }
  #pragma unroll
  for (int o = 32; o; o >>= 1) s += __shfl_xor(s, o);
  const float m = s * (1.f/320.f);
  #pragma unroll
  for (int k = 0; k < 5; ++k) p[lane + 64*k] = v[k] - m;
}

// ---------------------------------------------------------------------------
// qksplit: f32 [b][c][h][w] (row-mean'd) -> split bf16 planes [row][u][c]
__global__ __launch_bounds__(256) void qksplit_kernel(
    const float* __restrict__ src,
    unsigned short* __restrict__ dstH, unsigned short* __restrict__ dstL) {
  const int ut = blockIdx.x, row = blockIdx.y;
  const int u0 = ut * 64;
  const int b = row / H_, hh = row - b*H_;
  const int tid = threadIdx.x;
  __shared__ float Tf[64][65];   // [c][u]
  for (int i = tid; i < 1024; i += 256) {
    int c = i >> 4, q = i & 15;
    *(float4*)&Tf[c][4*q] =
        *(const float4*)&src[((size_t)(b*64 + c)*H_ + hh)*W_ + u0 + 4*q];
  }
  __syncthreads();
  for (int i = tid; i < 512; i += 256) {
    int u = i >> 3, j = i & 7;
    unsigned hi[8], lo[8];
    #pragma unroll
    for (int k = 0; k < 8; ++k) {
      float v = Tf[j*8 + k][u];
      unsigned hh32 = f2bf1(v);
      hi[k] = hh32;
      lo[k] = f2bf1(v - __uint_as_float(hh32 << 16));
    }
    unsigned ph[4], pl[4];
    #pragma unroll
    for (int k = 0; k < 4; ++k) {
      ph[k] = hi[2*k] | (hi[2*k+1] << 16);
      pl[k] = lo[2*k] | (lo[2*k+1] << 16);
    }
    const size_t dst = ((size_t)row*320 + u0 + u)*64 + j*8;
    *(uint4*)&dstH[dst] = *(uint4*)&ph[0];
    *(uint4*)&dstL[dst] = *(uint4*)&pl[0];
  }
}

// xcvt: x_left/x_right f32 -> fp16 planes (same [b][c][h][w] layout)
__global__ __launch_bounds__(256) void xcvt_kernel(
    const float* __restrict__ xl, const float* __restrict__ xr,
    _Float16* __restrict__ dl, _Float16* __restrict__ dr) {
  const size_t i8 = ((size_t)blockIdx.x*256 + threadIdx.x) * 8;
  if (i8 >= QK_SZ) return;
  float4 a = *(const float4*)&xl[i8], b4 = *(const float4*)&xl[i8+4];
  h16x8 o = {(_Float16)a.x,(_Float16)a.y,(_Float16)a.z,(_Float16)a.w,
             (_Float16)b4.x,(_Float16)b4.y,(_Float16)b4.z,(_Float16)b4.w};
  *(h16x8*)&dl[i8] = o;
  a = *(const float4*)&xr[i8]; b4 = *(const float4*)&xr[i8+4];
  h16x8 o2 = {(_Float16)a.x,(_Float16)a.y,(_Float16)a.z,(_Float16)a.w,
              (_Float16)b4.x,(_Float16)b4.y,(_Float16)b4.z,(_Float16)b4.w};
  *(h16x8*)&dr[i8] = o2;
}

// ---------------------------------------------------------------------------
// stats: LDS fragment planes, staged via pure 16B copies from global planes.
// XCD-chunked swizzle: all 5 ub-blocks of a row on one XCD (1600 = 8*200).
__global__ __launch_bounds__(256, 4) void stats_kernel(
    const unsigned short* __restrict__ QHg, const unsigned short* __restrict__ QLg,
    const unsigned short* __restrict__ KHg, const unsigned short* __restrict__ KLg,
    float* __restrict__ rsum, float* __restrict__ cspart) {
  const int bid = blockIdx.x;
  const int swz = (bid & 7) * 200 + (bid >> 3);
  const int row = swz / 5, ub = swz - row*5;
  const int u0 = ub * 64;
  const int tid = threadIdx.x;
  const int lane = tid & 63, wv = tid >> 6;
  const int l15 = lane & 15, l4 = lane >> 4;
  __shared__ unsigned short QH[64*64], QL[64*64], KH[64*64], KL[64*64];
  __shared__ float rsw[256];
  const size_t pbase = (size_t)row * 320 * 64;

  // stage Q planes once (pure 16B copies, psw on LDS side)
  for (int i = tid; i < 512; i += 256) {
    int r = i >> 3, j = i & 7;
    const size_t a = pbase + (size_t)(u0 + r)*64 + j*8;
    *(s16x8*)&QH[psw(r, j*8)] = *(const s16x8*)&QHg[a];
    *(s16x8*)&QL[psw(r, j*8)] = *(const s16x8*)&QLg[a];
  }
  float rp[4] = {};
  for (int vb = 0; vb < 5; ++vb) {
    __syncthreads();
    for (int i = tid; i < 512; i += 256) {
      int r = i >> 3, j = i & 7;
      const size_t a = pbase + (size_t)(vb*64 + r)*64 + j*8;
      *(s16x8*)&KH[psw(r, j*8)] = *(const s16x8*)&KHg[a];
      *(s16x8*)&KL[psw(r, j*8)] = *(const s16x8*)&KLg[a];
    }
    __syncthreads();
    const int vr = (wv << 4) + l15;
    const s16x8 kh0 = *(const s16x8*)&KH[psw(vr, l4*8)];
    const s16x8 kh1 = *(const s16x8*)&KH[psw(vr, 32 + l4*8)];
    const s16x8 kl0 = *(const s16x8*)&KL[psw(vr, l4*8)];
    const s16x8 kl1 = *(const s16x8*)&KL[psw(vr, 32 + l4*8)];
    float cp[4] = {};
    #pragma unroll
    for (int t = 0; t < 4; ++t) {
      const int qrow = t*16 + l15;
      const s16x8 qh0 = *(const s16x8*)&QH[psw(qrow, l4*8)];
      const s16x8 qh1 = *(const s16x8*)&QH[psw(qrow, 32 + l4*8)];
      const s16x8 ql0 = *(const s16x8*)&QL[psw(qrow, l4*8)];
      const s16x8 ql1 = *(const s16x8*)&QL[psw(qrow, 32 + l4*8)];
      f32x4 s = {};
      s = __builtin_amdgcn_mfma_f32_16x16x32_bf16(kh0, qh0, s, 0, 0, 0);
      s = __builtin_amdgcn_mfma_f32_16x16x32_bf16(kh1, qh1, s, 0, 0, 0);
      s = __builtin_amdgcn_mfma_f32_16x16x32_bf16(kl0, qh0, s, 0, 0, 0);
      s = __builtin_amdgcn_mfma_f32_16x16x32_bf16(kl1, qh1, s, 0, 0, 0);
      s = __builtin_amdgcn_mfma_f32_16x16x32_bf16(kh0, ql0, s, 0, 0, 0);
      s = __builtin_amdgcn_mfma_f32_16x16x32_bf16(kh1, ql1, s, 0, 0, 0);
      float e0 = __expf(s[0]), e1 = __expf(s[1]), e2 = __expf(s[2]), e3 = __expf(s[3]);
      rp[t] += e0 + e1 + e2 + e3;
      cp[0] += e0; cp[1] += e1; cp[2] += e2; cp[3] += e3;
    }
    #pragma unroll
    for (int r = 0; r < 4; ++r) {
      float v = cp[r];
      v += __shfl_xor(v, 1); v += __shfl_xor(v, 2);
      v += __shfl_xor(v, 4); v += __shfl_xor(v, 8);
      cp[r] = v;
    }
    if (l15 == 0) {
      f32x4 cw = {cp[0], cp[1], cp[2], cp[3]};
      *(f32x4*)&cspart[((size_t)row*5 + ub)*W_ + vb*64 + (wv << 4) + (l4 << 2)] = cw;
    }
  }
  #pragma unroll
  for (int t = 0; t < 4; ++t) {
    float v = rp[t];
    v += __shfl_xor(v, 16); v += __shfl_xor(v, 32);
    rp[t] = v;
  }
  if (l4 == 0) {
    #pragma unroll
    for (int t = 0; t < 4; ++t) rsw[(wv << 6) + (t << 4) + l15] = rp[t];
  }
  __syncthreads();
  if (tid < 64)
    rsum[(size_t)row*W_ + u0 + tid] = rsw[tid] + rsw[64+tid] + rsw[128+tid] + rsw[192+tid];
}

__global__ __launch_bounds__(256) void csreduce_kernel(
    const float* __restrict__ csp, float* __restrict__ csum) {
  int idx = blockIdx.x*256 + threadIdx.x;
  if (idx >= (int)RS_SZ) return;
  int row = idx / W_, v = idx - row*W_;
  float s = 0.f;
  #pragma unroll
  for (int ub = 0; ub < 5; ++ub) s += csp[((size_t)row*5 + ub)*W_ + v];
  csum[idx] = s;
}

// ---------------------------------------------------------------------------
__device__ __forceinline__ int halo_u(int k, int u0) {
  if (k < 64) return u0 + k;
  return (k == 64) ? (u0-2) : (k == 65) ? (u0-1) : (k == 66) ? (u0+64) : (u0+65);
}

// attn: LDS-plane structure, staged via pure 16B copies from the precomputed
// global split planes. XCD-chunked swizzle.
__global__ __launch_bounds__(256, 3) void attn_kernel(
    const unsigned short* __restrict__ QHg, const unsigned short* __restrict__ QLg,
    const unsigned short* __restrict__ KHg, const unsigned short* __restrict__ KLg,
    const float* __restrict__ rsump, const float* __restrict__ csump,
    const _Float16* __restrict__ xh, const float* __restrict__ xblend,
    float* __restrict__ outp) {
  const int bid = blockIdx.x;
  const int swz = (bid & 7) * 200 + (bid >> 3);
  const int row = swz / 5, ub = swz - row*5;
  const int b = row / H_, h = row - b*H_;
  const int u0 = ub * 64;
  const int tid = threadIdx.x;
  const int lane = tid & 63, wv = tid >> 6;
  const int l15 = lane & 15, l4 = lane >> 4;

  __shared__ unsigned short QH[68*64], QL[68*64];   // Q split [u 0..67][c]
  __shared__ unsigned short KH[64*64], KL[64*64];   // K split [v][c]
  __shared__ _Float16 Xh[64*64];                    // x fp16 [c][v]
  __shared__ _Float16 Ph[68*64];                    // P fp16 [u 0..67][v]
  __shared__ float rinv[80];                        // 68..79 = 0
  __shared__ float Vw[256], Vt[64];

  const size_t rowoff = (size_t)b*C0_*HW_ + (size_t)h*W_;
  const size_t pbase = (size_t)row * 320 * 64;
  const float* rsrow = rsump + (size_t)row*W_;
  const float* csrow = csump + (size_t)row*W_;

  if (tid < 80) rinv[tid] = 0.f;
  if (tid < 68) {
    const int u = halo_u(tid, u0);
    rinv[tid] = (u >= 0 && u < W_) ? (1.f / rsrow[u]) : 0.f;
  }
  // Q staging once: 68 rows x 8 chunks per plane, pure 16B copies
  for (int i = tid; i < 544; i += 256) {
    int r = i >> 3, j = i & 7;
    int u = halo_u(r, u0);
    s16x8 vh = {}, vl = {};
    if (u >= 0 && u < W_) {
      const size_t a = pbase + (size_t)u*64 + j*8;
      vh = *(const s16x8*)&QHg[a];
      vl = *(const s16x8*)&QLg[a];
    }
    *(s16x8*)&QH[psw(r, j*8)] = vh;
    *(s16x8*)&QL[psw(r, j*8)] = vl;
  }

  f32x4 xacc[4] = {};
  float vsum[4] = {};
  const int vq4 = (wv << 4) + (l4 << 2);

  for (int vb = 0; vb < 5; ++vb) {
    const int v0 = vb * 64;
    __syncthreads();
    // stage K planes + x plane (16B copies)
    for (int i = tid; i < 512; i += 256) {
      int r = i >> 3, j = i & 7;
      const size_t a = pbase + (size_t)(v0 + r)*64 + j*8;
      *(s16x8*)&KH[psw(r, j*8)] = *(const s16x8*)&KHg[a];
      *(s16x8*)&KL[psw(r, j*8)] = *(const s16x8*)&KLg[a];
    }
    for (int i = tid; i < 512; i += 256) {
      int c = i >> 3, j = i & 7;
      const size_t xa = ((size_t)(b*64 + c)*H_ + h)*W_ + v0 + j*8;
      *(h16x8*)&Xh[psw(c, j*8)] = *(const h16x8*)&xh[xa];
    }
    __syncthreads();

    // ---- S phase: A = K rows (m = v), B = Q rows (n = u)
    const int vr = (wv << 4) + l15;
    const s16x8 kh0 = *(const s16x8*)&KH[psw(vr, l4*8)];
    const s16x8 kh1 = *(const s16x8*)&KH[psw(vr, 32 + l4*8)];
    const s16x8 kl0 = *(const s16x8*)&KL[psw(vr, l4*8)];
    const s16x8 kl1 = *(const s16x8*)&KL[psw(vr, 32 + l4*8)];
    float P[5][4];
    #pragma unroll
    for (int t = 0; t < 5; ++t) {
      const int qrow = (t < 4) ? (t*16 + l15) : (64 + (l15 & 3));
      const s16x8 qh0 = *(const s16x8*)&QH[psw(qrow, l4*8)];
      const s16x8 qh1 = *(const s16x8*)&QH[psw(qrow, 32 + l4*8)];
      const s16x8 ql0 = *(const s16x8*)&QL[psw(qrow, l4*8)];
      const s16x8 ql1 = *(const s16x8*)&QL[psw(qrow, 32 + l4*8)];
      f32x4 s = {};
      s = __builtin_amdgcn_mfma_f32_16x16x32_bf16(kh0, qh0, s, 0, 0, 0);
      s = __builtin_amdgcn_mfma_f32_16x16x32_bf16(kh1, qh1, s, 0, 0, 0);
      s = __builtin_amdgcn_mfma_f32_16x16x32_bf16(kl0, qh0, s, 0, 0, 0);
      s = __builtin_amdgcn_mfma_f32_16x16x32_bf16(kl1, qh1, s, 0, 0, 0);
      s = __builtin_amdgcn_mfma_f32_16x16x32_bf16(kh0, ql0, s, 0, 0, 0);
      s = __builtin_amdgcn_mfma_f32_16x16x32_bf16(kh1, ql1, s, 0, 0, 0);
      const float ri = rinv[(t < 4) ? (t*16 + l15) : (64 + l15)];   // 0 for pad/OOB
      #pragma unroll
      for (int r = 0; r < 4; ++r) P[t][r] = __expf(s[r]) * ri;
    }
    // write P to fp16 plane: core rows + halo rows
    #pragma unroll
    for (int t = 0; t < 4; ++t) {
      h16x4 hp = {(_Float16)P[t][0], (_Float16)P[t][1], (_Float16)P[t][2], (_Float16)P[t][3]};
      *(h16x4*)&Ph[psw(t*16 + l15, vq4)] = hp;
    }
    if (l15 < 4) {
      h16x4 hp = {(_Float16)P[4][0], (_Float16)P[4][1], (_Float16)P[4][2], (_Float16)P[4][3]};
      *(h16x4*)&Ph[psw(64 + l15, vq4)] = hp;
    }
    __syncthreads();

    // ---- xT phase: A = P rows (m = u), B = x rows (n = c)
    {
      const int ur = (wv << 4) + l15;
      const h16x8 pa0 = *(const h16x8*)&Ph[psw(ur, l4*8)];
      const h16x8 pa1 = *(const h16x8*)&Ph[psw(ur, 32 + l4*8)];
      #pragma unroll
      for (int t = 0; t < 4; ++t) {
        const int crow = t*16 + l15;
        const h16x8 xb0 = *(const h16x8*)&Xh[psw(crow, l4*8)];
        const h16x8 xb1 = *(const h16x8*)&Xh[psw(crow, 32 + l4*8)];
        xacc[t] = __builtin_amdgcn_mfma_f32_16x16x32_f16(pa0, xb0, xacc[t], 0, 0, 0);
        xacc[t] = __builtin_amdgcn_mfma_f32_16x16x32_f16(pa1, xb1, xacc[t], 0, 0, 0);
      }
    }

    // ---- banded V: d=0 from f32 regs, neighbors from fp16 plane
    {
      const float4 cs4 = *(const float4*)&csrow[v0 + vq4];
      const float ci[4] = {1.f/cs4.x, 1.f/cs4.y, 1.f/cs4.z, 1.f/cs4.w};
      #pragma unroll
      for (int t = 0; t < 4; ++t) {
        float w[4] = {P[t][0], P[t][1], P[t][2], P[t][3]};
        #pragma unroll
        for (int d = -2; d <= 2; ++d) {
          if (d == 0) continue;
          const int q = t*16 + l15 + d;
          const int rr = (q < 0) ? (66 + q) : ((q > 63) ? (q + 2) : q);
          const h16x4 pn = *(const h16x4*)&Ph[psw(rr, vq4)];
          w[0] += (float)pn[0]; w[1] += (float)pn[1];
          w[2] += (float)pn[2]; w[3] += (float)pn[3];
        }
        #pragma unroll
        for (int r = 0; r < 4; ++r)
          vsum[t] = fmaf(P[t][r] * ci[r], w[r], vsum[t]);
      }
    }
  }

  // V reduce: over l4 (shfl bits 4,5), then across waves via LDS
  #pragma unroll
  for (int t = 0; t < 4; ++t) {
    float v = vsum[t];
    v += __shfl_xor(v, 16); v += __shfl_xor(v, 32);
    vsum[t] = v;
  }
  if (l4 == 0) {
    #pragma unroll
    for (int t = 0; t < 4; ++t) Vw[(wv << 6) + (t << 4) + l15] = vsum[t];
  }
  __syncthreads();
  if (tid < 64) {
    float v = Vw[tid] + Vw[64+tid] + Vw[128+tid] + Vw[192+tid];
    Vt[tid] = tanhf(5.f * v * rsrow[u0 + tid]);
  }
  __syncthreads();

  // epilogue: lane holds xT[u = wv*16 + l4*4 + r][c = t*16 + l15]
  const int ubu = (wv << 4) + (l4 << 2);
  float tv[4];
  #pragma unroll
  for (int r = 0; r < 4; ++r) tv[r] = Vt[ubu + r];
  #pragma unroll
  for (int t = 0; t < 4; ++t) {
    const int c = (t << 4) + l15;
    const size_t base = rowoff + (size_t)c*HW_ + u0 + ubu;
    const float4 xb4 = *(const float4*)&xblend[base];
    float4 o4;
    o4.x = xb4.x * (1.f - tv[0]) + xacc[t][0] * tv[0];
    o4.y = xb4.y * (1.f - tv[1]) + xacc[t][1] * tv[1];
    o4.z = xb4.z * (1.f - tv[2]) + xacc[t][2] * tv[2];
    o4.w = xb4.w * (1.f - tv[3]) + xacc[t][3] * tv[3];
    *(float4*)&outp[base] = o4;
  }
}

// ---------------------------------------------------------------------------
extern "C" void kernel_launch(void* const* d_in, const int* in_sizes, int n_in,
                              void* d_out, int out_size, void* d_ws, size_t ws_size,
                              hipStream_t stream) {
  const float* x_left  = (const float*)d_in[0];
  const float* x_right = (const float*)d_in[1];
  const float* catL    = (const float*)d_in[2];
  const float* catR    = (const float*)d_in[3];
  const float* bq_w    = (const float*)d_in[4];
  const float* bq_b    = (const float*)d_in[5];
  const float* bs_w    = (const float*)d_in[6];
  const float* bs_b    = (const float*)d_in[7];
  const float* rb_w1   = (const float*)d_in[8];
  const float* rb_b1   = (const float*)d_in[9];
  const float* rb_w2   = (const float*)d_in[10];
  const float* rb_b2   = (const float*)d_in[11];
  const float* gamma   = (const float*)d_in[12];
  const float* beta    = (const float*)d_in[13];

  float* ws = (float*)d_ws;
  size_t off = 0;
  float* WfQ = ws + off; off += WFQ_SZ;
  float* WfK = ws + off; off += WFQ_SZ;
  unsigned short* Wb   = (unsigned short*)(ws + off); off += WB_SZ;
  unsigned short* W2bQ = (unsigned short*)(ws + off); off += W2B_SZ;
  unsigned short* W2bK = (unsigned short*)(ws + off); off += W2B_SZ;
  float* ab  = ws + off; off += AB_SZ;
  float* bfQ = ws + off; off += BF_SZ;
  float* bfK = ws + off; off += BF_SZ;
  float2* pb = (float2*)(ws + off); off += PB_SZ;
  unsigned short* t1   = (unsigned short*)(ws + off); off += T1_SZ;
  unsigned short* catb = (unsigned short*)(ws + off); off += CATB_SZ;
  float* Qb  = ws + off; off += QK_SZ;
  float* Kb  = ws + off; off += QK_SZ;
  float* rsb = ws + off; off += RS_SZ;
  float* csb = ws + off; off += RS_SZ;
  float* csp = ws + off; off += CSP_SZ;

  // aliases: split planes live in catb's space, xh planes in t1's space
  unsigned short* QHg = catb;
  unsigned short* QLg = catb + 6553600;
  unsigned short* KHg = catb + 13107200;
  unsigned short* KLg = catb + 19660800;
  _Float16* xhL = (_Float16*)t1;
  _Float16* xhR = xhL + 6553600;

  wtrans_kernel<<<576, 256, 0, stream>>>(rb_w1, rb_w2, bq_w, bs_w, Wb, WfQ, WfK);
  bnstats1_kernel<<<4096, 320, 0, stream>>>(catL, catR, pb);
  bnstats2_kernel<<<2, 256, 0, stream>>>(pb, gamma, beta, ab);
  prep2_kernel<<<160, 256, 0, stream>>>(bq_w, bs_w, bq_b, bs_b, rb_b2,
                                        WfQ, WfK, W2bQ, W2bK, bfQ, bfK);

  dim3 agrid(HW_/64, 1, 8);
  dim3 cgrid(5, 80, 8);
  // left -> Q
  bnapply_kernel<<<agrid, 256, 0, stream>>>(catL, ab, catb);
  conv1_mfma<<<cgrid, 256, 0, stream>>>(catb, Wb, rb_b1, t1);
  conv2_mfma<<<cgrid, 256, 0, stream>>>(t1, catb, W2bQ, bfQ, Qb);
  // right -> K
  bnapply_kernel<<<agrid, 256, 0, stream>>>(catR, ab + 512, catb);
  conv1_mfma<<<cgrid, 256, 0, stream>>>(catb, Wb, rb_b1, t1);
  conv2_mfma<<<cgrid, 256, 0, stream>>>(t1, catb, W2bK, bfK, Kb);

  rowmean_kernel<<<B_*C0_*H_, 64, 0, stream>>>(Qb);
  rowmean_kernel<<<B_*C0_*H_, 64, 0, stream>>>(Kb);

  // build split planes (overwrites catb space) and fp16 x planes (t1 space)
  qksplit_kernel<<<dim3(5, NROWS_), 256, 0, stream>>>(Qb, QHg, QLg);
  qksplit_kernel<<<dim3(5, NROWS_), 256, 0, stream>>>(Kb, KHg, KLg);
  xcvt_kernel<<<3200, 256, 0, stream>>>(x_left, x_right, xhL, xhR);

  stats_kernel<<<1600, 256, 0, stream>>>(QHg, QLg, KHg, KLg, rsb, csp);
  csreduce_kernel<<<(int)((RS_SZ + 255)/256), 256, 0, stream>>>(csp, csb);

  float* outL = (float*)d_out;
  float* outR = outL + QK_SZ;
  attn_kernel<<<1600, 256, 0, stream>>>(QHg, QLg, KHg, KLg,
                                        rsb, csb, xhR, x_left, outL);
  attn_kernel<<<1600, 256, 0, stream>>>(KHg, KLg, QHg, QLg,
                                        csb, rsb, xhL, x_right, outR);
}